// Round 5
// baseline (419.427 us; speedup 1.0000x reference)
//
#include <hip/hip_runtime.h>
#include <stdint.h>

#define NB 2
#define NSQ 2048
#define NSK 2048
#define ND 1024
#define NH 16
#define NDH 64

typedef unsigned short u16;
typedef unsigned int u32;
typedef __bf16 bf16x8_t __attribute__((ext_vector_type(8)));
typedef float f32x4_t __attribute__((ext_vector_type(4)));
typedef u32 u32x4_t __attribute__((ext_vector_type(4)));

__device__ __forceinline__ float bf2f(u16 u) {
    union { float f; u32 i; } v; v.i = ((u32)u) << 16; return v.f;
}
__device__ __forceinline__ u16 f2bf(float x) {
    union { float f; u32 i; } v; v.f = x;
    u32 r = v.i + 0x7fffu + ((v.i >> 16) & 1u);
    return (u16)(r >> 16);
}
__device__ __forceinline__ u32 fbits(float x) {
    union { float f; u32 i; } v; v.f = x; return v.i;
}
__device__ __forceinline__ float bitsf(u32 x) {
    union { float f; u32 i; } v; v.i = x; return v.f;
}

// ---------------------------------------------------------------- dtype detect
__global__ __launch_bounds__(256) void detect_kernel(
    const u16* __restrict__ Q, int* __restrict__ flag)
{
    __shared__ int s;
    if (threadIdx.x == 0) s = 0;
    __syncthreads();
    uint2 x = ((const uint2*)Q)[threadIdx.x];
    u16 a0 = x.x & 0xffff, a1 = x.x >> 16, a2 = x.y & 0xffff, a3 = x.y >> 16;
    bool big = (((a0 >> 7) & 0xff) >= 0x8D) || (((a1 >> 7) & 0xff) >= 0x8D) ||
               (((a2 >> 7) & 0xff) >= 0x8D) || (((a3 >> 7) & 0xff) >= 0x8D);
    if (big) s = 1;
    __syncthreads();
    if (threadIdx.x == 0) *flag = s;   // 1 = f32 inputs, 0 = bf16 inputs
}

// ---------------------------------------------------------------- param canon
// canonical vec order: bq,bk,bv,bo, ln_q_g,ln_q_b, ln_kv_g,ln_kv_b, ln_f_g,ln_f_b
__global__ __launch_bounds__(256) void cvt_params_kernel(
    const int* __restrict__ flag,
    const void* __restrict__ Wq, const void* __restrict__ Wk,
    const void* __restrict__ Wv, const void* __restrict__ Wo,
    const void* __restrict__ vbq, const void* __restrict__ vbk,
    const void* __restrict__ vbv, const void* __restrict__ vbo,
    const void* __restrict__ g0, const void* __restrict__ b0,
    const void* __restrict__ g1, const void* __restrict__ b1,
    const void* __restrict__ g2, const void* __restrict__ b2,
    u16* __restrict__ Wc, u16* __restrict__ Vc)
{
    int blk = blockIdx.x;
    const void* src;
    u16* dst;
    size_t srcoff;
    if (blk < 4096) {
        int w = blk >> 10;
        src = (w == 0) ? Wq : (w == 1) ? Wk : (w == 2) ? Wv : Wo;
        srcoff = (size_t)(blk & 1023) * 1024;
        dst = Wc + (size_t)w * 1024 * 1024 + srcoff;
    } else {
        int v = blk - 4096;
        src = (v == 0) ? vbq : (v == 1) ? vbk : (v == 2) ? vbv : (v == 3) ? vbo :
              (v == 4) ? g0  : (v == 5) ? b0  : (v == 6) ? g1  : (v == 7) ? b1 :
              (v == 8) ? g2  : b2;
        srcoff = 0;
        dst = Vc + (size_t)v * 1024;
    }
    int t = threadIdx.x;
    u32 lo, hi;
    if (*flag) {
        float4 x = ((const float4*)src)[srcoff / 4 + t];
        lo = (u32)f2bf(x.x) | ((u32)f2bf(x.y) << 16);
        hi = (u32)f2bf(x.z) | ((u32)f2bf(x.w) << 16);
    } else {
        uint2 x = ((const uint2*)src)[srcoff / 4 + t];
        lo = x.x; hi = x.y;
    }
    uint2 o; o.x = lo; o.y = hi;
    ((uint2*)dst)[t] = o;
}

// ---------------------------------------------------------------- LN (inputs)
__global__ __launch_bounds__(256) void ln_in_kernel(
    const int* __restrict__ flag,
    const void* __restrict__ Q, const void* __restrict__ K,
    const u16* __restrict__ Vc,
    u16* __restrict__ Qn, u16* __restrict__ Kn)
{
    int row = blockIdx.x;
    const void* x; const u16 *g, *bb; u16* y;
    size_t roff;
    if (row < NB * NSQ) {
        x = Q; roff = (size_t)row * ND;
        g = Vc + 4 * 1024; bb = Vc + 5 * 1024;
        y = Qn + roff;
    } else {
        int r2 = row - NB * NSQ;
        x = K; roff = (size_t)r2 * ND;
        g = Vc + 6 * 1024; bb = Vc + 7 * 1024;
        y = Kn + roff;
    }
    int t = threadIdx.x;
    float v0, v1, v2, v3;
    if (*flag) {
        float4 xv = ((const float4*)x)[roff / 4 + t];
        v0 = xv.x; v1 = xv.y; v2 = xv.z; v3 = xv.w;
    } else {
        uint2 ux = ((const uint2*)x)[roff / 4 + t];
        v0 = bf2f(ux.x & 0xffff); v1 = bf2f(ux.x >> 16);
        v2 = bf2f(ux.y & 0xffff); v3 = bf2f(ux.y >> 16);
    }
    float s1 = v0 + v1 + v2 + v3;
    float s2 = v0*v0 + v1*v1 + v2*v2 + v3*v3;
#pragma unroll
    for (int off = 32; off >= 1; off >>= 1) {
        s1 += __shfl_xor(s1, off);
        s2 += __shfl_xor(s2, off);
    }
    __shared__ float r1[4], r2[4];
    int wave = t >> 6;
    if ((t & 63) == 0) { r1[wave] = s1; r2[wave] = s2; }
    __syncthreads();
    float t1 = r1[0] + r1[1] + r1[2] + r1[3];
    float t2 = r2[0] + r2[1] + r2[2] + r2[3];
    float mean = t1 * (1.0f / ND);
    float var  = t2 * (1.0f / ND) - mean * mean;
    float rstd = rsqrtf(var + 1e-5f);
    uint2 ug = ((const uint2*)g)[t];
    uint2 ub = ((const uint2*)bb)[t];
    float y0 = (v0 - mean) * rstd * bf2f(ug.x & 0xffff) + bf2f(ub.x & 0xffff);
    float y1 = (v1 - mean) * rstd * bf2f(ug.x >> 16)    + bf2f(ub.x >> 16);
    float y2 = (v2 - mean) * rstd * bf2f(ug.y & 0xffff) + bf2f(ub.y & 0xffff);
    float y3 = (v3 - mean) * rstd * bf2f(ug.y >> 16)    + bf2f(ub.y >> 16);
    uint2 o;
    o.x = (u32)f2bf(y0) | ((u32)f2bf(y1) << 16);
    o.y = (u32)f2bf(y2) | ((u32)f2bf(y3) << 16);
    ((uint2*)y)[t] = o;
}

// ---------------------------------------------------------------- fused 4x GEMM
// z=0: (Qn@Wq^T+bq)/32 -> Q1 ; z=1: Kn@Wk^T+bk -> K1
// z=2: Kn@Wv^T+bv -> V1 (normal layout; transposed later)
// z=3: relu(Qn@Wo^T+bo) -> R
// Staging via global_load_lds width=16 (m97 structure).
__global__ __launch_bounds__(256) void gemm4_kernel(
    const u16* __restrict__ Qn, const u16* __restrict__ Kn,
    const u16* __restrict__ Wc, const u16* __restrict__ Vc,
    u16* __restrict__ Q1, u16* __restrict__ K1, u16* __restrict__ V1,
    u16* __restrict__ R)
{
    int z = blockIdx.z;
    const u16* X    = (z == 0 || z == 3) ? Qn : Kn;
    const u16* W    = Wc + (size_t)z * 1024 * 1024;
    const u16* bias = Vc + (size_t)z * 1024;

    __shared__ u16 sA[128 * 32];
    __shared__ u16 sB[128 * 32];

    int tid  = threadIdx.x;
    int wave = tid >> 6, lane = tid & 63;
    int wm = wave >> 1, wn = wave & 1;
    int m0 = blockIdx.x * 128;
    int n0 = blockIdx.y * 128;

    f32x4_t acc[4][4];
#pragma unroll
    for (int i = 0; i < 4; ++i)
#pragma unroll
        for (int j = 0; j < 4; ++j)
            acc[i][j] = (f32x4_t){0.f, 0.f, 0.f, 0.f};

    int lrow = lane >> 2;            // 0..15
    int lcol = (lane & 3) * 8;       // u16 col within 32

    for (int kb = 0; kb < ND / 32; ++kb) {
        __syncthreads();             // prior iteration's ds_reads complete
        int k0 = kb * 32;
#pragma unroll
        for (int r = 0; r < 2; ++r) {
            int rowb = (r * 4 + wave) * 16;   // wave-uniform
            const u16* ga = X + (size_t)(m0 + rowb + lrow) * ND + k0 + lcol;
            const u16* gb = W + (size_t)(n0 + rowb + lrow) * ND + k0 + lcol;
            __builtin_amdgcn_global_load_lds(
                (const __attribute__((address_space(1))) u32*)ga,
                (__attribute__((address_space(3))) u32*)(sA + rowb * 32), 16, 0, 0);
            __builtin_amdgcn_global_load_lds(
                (const __attribute__((address_space(1))) u32*)gb,
                (__attribute__((address_space(3))) u32*)(sB + rowb * 32), 16, 0, 0);
        }
        __syncthreads();             // vmcnt drained -> LDS data visible

        bf16x8_t af[4], bfr[4];
#pragma unroll
        for (int tm = 0; tm < 4; ++tm) {
            int rr = wm * 64 + tm * 16 + (lane & 15);
            af[tm] = *(const bf16x8_t*)(sA + rr * 32 + (lane >> 4) * 8);
        }
#pragma unroll
        for (int tn = 0; tn < 4; ++tn) {
            int rr = wn * 64 + tn * 16 + (lane & 15);
            bfr[tn] = *(const bf16x8_t*)(sB + rr * 32 + (lane >> 4) * 8);
        }
#pragma unroll
        for (int tm = 0; tm < 4; ++tm)
#pragma unroll
            for (int tn = 0; tn < 4; ++tn)
                acc[tm][tn] = __builtin_amdgcn_mfma_f32_16x16x32_bf16(
                    af[tm], bfr[tn], acc[tm][tn], 0, 0, 0);
    }

    u16* outp = (z == 0) ? Q1 : (z == 1) ? K1 : (z == 2) ? V1 : R;
#pragma unroll
    for (int tm = 0; tm < 4; ++tm) {
#pragma unroll
        for (int tn = 0; tn < 4; ++tn) {
            int n = n0 + wn * 64 + tn * 16 + (lane & 15);
            float bv_ = bf2f(bias[n]);
#pragma unroll
            for (int r = 0; r < 4; ++r) {
                int m = m0 + wm * 64 + tm * 16 + (lane >> 4) * 4 + r;
                float val = acc[tm][tn][r] + bv_;
                if (z == 0) val *= 0.03125f;          // fold 1/sqrt(D)
                if (z == 3) val = fmaxf(val, 0.f);
                outp[(size_t)m * ND + n] = f2bf(val);
            }
        }
    }
}

// ---------------------------------------------------------------- V transpose
// V1 [b][key][h][d] -> V1t [b][h][d][key], 64x64 tiles through LDS.
__global__ __launch_bounds__(256) void vtrans_kernel(
    const u16* __restrict__ V1, u16* __restrict__ V1t)
{
    int kb = blockIdx.x;   // key tile, 0..31
    int h  = blockIdx.y;
    int b  = blockIdx.z;
    __shared__ u16 sT[64 * 72];
    int tid = threadIdx.x;
    {
        int row = tid >> 3, seg = tid & 7;   // row 0..31
        const u16* gv = V1 + (size_t)(b * NSK + kb * 64 + row) * ND + h * NDH + seg * 8;
        *(uint4*)(sT + row * 72 + seg * 8)        = *(const uint4*)gv;
        *(uint4*)(sT + (row + 32) * 72 + seg * 8) = *(const uint4*)(gv + (size_t)32 * ND);
    }
    __syncthreads();
    int d = tid >> 2, sg = tid & 3;          // d 0..63; two 16B segs per thread
    u16 buf[16];
#pragma unroll
    for (int i = 0; i < 8; ++i) buf[i]     = sT[(sg * 8 + i) * 72 + d];
#pragma unroll
    for (int i = 0; i < 8; ++i) buf[8 + i] = sT[((sg + 4) * 8 + i) * 72 + d];
    u16* go = V1t + ((size_t)(b * NH + h) * NDH + d) * NSK + kb * 64;
    *(uint4*)(go + sg * 8)       = *(uint4*)buf;
    *(uint4*)(go + (sg + 4) * 8) = *(uint4*)(buf + 8);
}

// ---------------------------------------------------------------- flash attention
// S^T = K.Q^T formulation; K/V fragments straight from global (no LDS, no
// k-loop barriers, zero bank conflicts). grid (SQ/64, H, B); 4 waves/block,
// wave w owns q rows w*16..+15. Accumulates O1 into R.
__global__ __launch_bounds__(256, 4) void attn_kernel(
    const u16* __restrict__ Q1, const u16* __restrict__ K1,
    const u16* __restrict__ V1t, const int* __restrict__ mask,
    u16* __restrict__ R)
{
    int q0 = blockIdx.x * 64;
    int h  = blockIdx.y;
    int b  = blockIdx.z;

    __shared__ float sM[2048];

    int tid  = threadIdx.x;
    int wave = tid >> 6, lane = tid & 63;
    int quad = lane >> 4, l4 = lane & 15;

    for (int i = tid; i < 512; i += 256) {
        int4 mi = ((const int4*)(mask + b * NSK))[i];
        float4 mf; mf.x = (float)mi.x; mf.y = (float)mi.y;
        mf.z = (float)mi.z; mf.w = (float)mi.w;
        ((float4*)sM)[i] = mf;
    }
    __syncthreads();

    // Q B-operand fragments (once per block)
    bf16x8_t qf[2];
    {
        const u16* qp = Q1 + (size_t)(b * NSQ + q0 + wave * 16 + l4) * ND + h * NDH;
        qf[0] = *(const bf16x8_t*)(qp + quad * 8);
        qf[1] = *(const bf16x8_t*)(qp + 32 + quad * 8);
    }

    const u16* kbase = K1 + (size_t)b * NSK * ND + h * NDH;
    const u16* vbase = V1t + (size_t)(b * NH + h) * NDH * NSK;

    float m_run = -1e30f, l_run = 0.f;   // per-lane: q = l4
    f32x4_t acc_o[4];                    // O^T C-layout: d = T*16+quad*4+r, q = l4
#pragma unroll
    for (int T = 0; T < 4; ++T) acc_o[T] = (f32x4_t){0.f, 0.f, 0.f, 0.f};

    int srcA = (quad & 1) * 32 + l4;
    int srcB = srcA + 16;
    bool hi = lane >= 32;

    for (int kb = 0; kb < NSK / 64; ++kb) {
        int key0 = kb * 64;

        // K fragments: A-operand rows = keys
        bf16x8_t kf[2][4];
#pragma unroll
        for (int kk = 0; kk < 2; ++kk)
#pragma unroll
            for (int tm = 0; tm < 4; ++tm)
                kf[kk][tm] = *(const bf16x8_t*)(kbase +
                    (size_t)(key0 + tm * 16 + l4) * ND + kk * 32 + quad * 8);

        // S^T = K @ Q^T : C-layout key = tm*16+quad*4+r, col q = l4
        f32x4_t accs[4];
#pragma unroll
        for (int tm = 0; tm < 4; ++tm) accs[tm] = (f32x4_t){0.f, 0.f, 0.f, 0.f};
#pragma unroll
        for (int kk = 0; kk < 2; ++kk)
#pragma unroll
            for (int tm = 0; tm < 4; ++tm)
                accs[tm] = __builtin_amdgcn_mfma_f32_16x16x32_bf16(
                    kf[kk][tm], qf[kk], accs[tm], 0, 0, 0);

        // V^T fragments (issued early; consumed after softmax)
        bf16x8_t vf[2][4];
#pragma unroll
        for (int kk = 0; kk < 2; ++kk)
#pragma unroll
            for (int T = 0; T < 4; ++T)
                vf[kk][T] = *(const bf16x8_t*)(vbase +
                    (size_t)(T * 16 + l4) * NSK + key0 + kk * 32 + quad * 8);

        f32x4_t mv[4];
#pragma unroll
        for (int tm = 0; tm < 4; ++tm)
            mv[tm] = *(const f32x4_t*)(sM + key0 + tm * 16 + quad * 4);

        // in-register online softmax (per-lane scalar state)
        float mloc = -1e30f;
#pragma unroll
        for (int tm = 0; tm < 4; ++tm)
#pragma unroll
            for (int r = 0; r < 4; ++r) mloc = fmaxf(mloc, accs[tm][r]);
        mloc = fmaxf(mloc, __shfl_xor(mloc, 16));
        mloc = fmaxf(mloc, __shfl_xor(mloc, 32));
        float m_new = fmaxf(m_run, mloc);
        float alpha = __expf(m_run - m_new);
        float lsum = 0.f;
        u32 pk[4][2];
#pragma unroll
        for (int tm = 0; tm < 4; ++tm) {
            u32 pb[4];
#pragma unroll
            for (int r = 0; r < 4; ++r) {
                float p = __expf(accs[tm][r] - m_new) * mv[tm][r];
                u32 tb = fbits(p) & 0xffff0000u;
                lsum += bitsf(tb);
                pb[r] = tb;
            }
            pk[tm][0] = (pb[0] >> 16) | pb[1];
            pk[tm][1] = (pb[2] >> 16) | pb[3];
        }
        lsum += __shfl_xor(lsum, 16);
        lsum += __shfl_xor(lsum, 32);
        l_run = l_run * alpha + lsum;
        m_run = m_new;

#pragma unroll
        for (int T = 0; T < 4; ++T)
#pragma unroll
            for (int r = 0; r < 4; ++r) acc_o[T][r] *= alpha;

#pragma unroll
        for (int kk = 0; kk < 2; ++kk) {
            u32 a0 = __shfl((int)pk[kk * 2][0], srcA), a1 = __shfl((int)pk[kk * 2][1], srcA);
            u32 b0 = __shfl((int)pk[kk * 2 + 1][0], srcA), b1 = __shfl((int)pk[kk * 2 + 1][1], srcA);
            u32 c0 = __shfl((int)pk[kk * 2][0], srcB), c1 = __shfl((int)pk[kk * 2][1], srcB);
            u32 d0 = __shfl((int)pk[kk * 2 + 1][0], srcB), d1 = __shfl((int)pk[kk * 2 + 1][1], srcB);
            u32x4_t pr;
            pr.x = hi ? b0 : a0;
            pr.y = hi ? b1 : a1;
            pr.z = hi ? d0 : c0;
            pr.w = hi ? d1 : c1;
            bf16x8_t pf = __builtin_bit_cast(bf16x8_t, pr);
#pragma unroll
            for (int T = 0; T < 4; ++T)
                acc_o[T] = __builtin_amdgcn_mfma_f32_16x16x32_bf16(
                    vf[kk][T], pf, acc_o[T], 0, 0, 0);
        }
    }

    // epilogue: O[q][d] = acc_o / l ; R += O1 (uint2 RMW)
    float inv = l_run > 0.f ? 1.f / l_run : 0.f;
    u16* rp = R + (size_t)(b * NSQ + q0 + wave * 16 + l4) * ND + h * NDH;
#pragma unroll
    for (int T = 0; T < 4; ++T) {
        u16* p = rp + T * 16 + quad * 4;
        uint2 o2 = *(const uint2*)p;
        float e0 = acc_o[T][0] * inv + bf2f(o2.x & 0xffff);
        float e1 = acc_o[T][1] * inv + bf2f(o2.x >> 16);
        float e2 = acc_o[T][2] * inv + bf2f(o2.y & 0xffff);
        float e3 = acc_o[T][3] * inv + bf2f(o2.y >> 16);
        uint2 on;
        on.x = (u32)f2bf(e0) | ((u32)f2bf(e1) << 16);
        on.y = (u32)f2bf(e2) | ((u32)f2bf(e3) << 16);
        *(uint2*)p = on;
    }
}

// ---------------------------------------------------------------- final LN
__global__ __launch_bounds__(256) void ln_out_kernel(
    const int* __restrict__ flag,
    const void* __restrict__ Q, const u16* __restrict__ R,
    const u16* __restrict__ Vc, void* __restrict__ out)
{
    int row = blockIdx.x;
    size_t roff = (size_t)row * ND;
    int t = threadIdx.x;
    int f = *flag;
    float v0, v1, v2, v3;
    uint2 ur = ((const uint2*)(R + roff))[t];
    if (f) {
        float4 xq = ((const float4*)Q)[roff / 4 + t];
        v0 = xq.x; v1 = xq.y; v2 = xq.z; v3 = xq.w;
    } else {
        uint2 uq = ((const uint2*)Q)[roff / 4 + t];
        v0 = bf2f(uq.x & 0xffff); v1 = bf2f(uq.x >> 16);
        v2 = bf2f(uq.y & 0xffff); v3 = bf2f(uq.y >> 16);
    }
    v0 += bf2f(ur.x & 0xffff); v1 += bf2f(ur.x >> 16);
    v2 += bf2f(ur.y & 0xffff); v3 += bf2f(ur.y >> 16);
    float s1 = v0 + v1 + v2 + v3;
    float s2 = v0*v0 + v1*v1 + v2*v2 + v3*v3;
#pragma unroll
    for (int off = 32; off >= 1; off >>= 1) {
        s1 += __shfl_xor(s1, off);
        s2 += __shfl_xor(s2, off);
    }
    __shared__ float r1[4], r2[4];
    int wave = t >> 6;
    if ((t & 63) == 0) { r1[wave] = s1; r2[wave] = s2; }
    __syncthreads();
    float t1 = r1[0] + r1[1] + r1[2] + r1[3];
    float t2 = r2[0] + r2[1] + r2[2] + r2[3];
    float mean = t1 * (1.0f / ND);
    float var  = t2 * (1.0f / ND) - mean * mean;
    float rstd = rsqrtf(var + 1e-5f);
    const u16* g  = Vc + 8 * 1024;
    const u16* bb = Vc + 9 * 1024;
    uint2 ug = ((const uint2*)g)[t];
    uint2 ub = ((const uint2*)bb)[t];
    float y0 = (v0 - mean) * rstd * bf2f(ug.x & 0xffff) + bf2f(ub.x & 0xffff);
    float y1 = (v1 - mean) * rstd * bf2f(ug.x >> 16)    + bf2f(ub.x >> 16);
    float y2 = (v2 - mean) * rstd * bf2f(ug.y & 0xffff) + bf2f(ub.y & 0xffff);
    float y3 = (v3 - mean) * rstd * bf2f(ug.y >> 16)    + bf2f(ub.y >> 16);
    if (f) {
        float4 o; o.x = y0; o.y = y1; o.z = y2; o.w = y3;
        ((float4*)out)[roff / 4 + t] = o;
    } else {
        uint2 o;
        o.x = (u32)f2bf(y0) | ((u32)f2bf(y1) << 16);
        o.y = (u32)f2bf(y2) | ((u32)f2bf(y3) << 16);
        ((uint2*)out)[roff / 4 + t] = o;
    }
}

// ---------------------------------------------------------------- launch
extern "C" void kernel_launch(void* const* d_in, const int* in_sizes, int n_in,
                              void* d_out, int out_size, void* d_ws, size_t ws_size,
                              hipStream_t stream) {
    const void* Q        = d_in[0];
    const void* K        = d_in[1];
    const int* pad_mask  = (const int*)d_in[2];

    const size_t NEL = (size_t)NB * NSQ * ND;   // 4,194,304
    int* flag = (int*)d_ws;
    u16* base = (u16*)d_ws + 128;
    u16* Qn  = base;
    u16* Kn  = Qn + NEL;
    u16* Q1  = Kn + NEL;
    u16* K1  = Q1 + NEL;
    u16* V1  = K1 + NEL;                         // normal layout from gemm
    u16* R   = V1 + NEL;                         // O2 then O1+O2
    u16* Wc  = R + NEL;                          // 4 x 1M canonical weights
    u16* Vc  = Wc + (size_t)4 * 1024 * 1024;     // 10 x 1024 canonical vectors
    u16* V1t = Qn;                               // aliases Qn (dead after gemm4)

    detect_kernel<<<dim3(1), dim3(256), 0, stream>>>((const u16*)Q, flag);

    cvt_params_kernel<<<dim3(4106), dim3(256), 0, stream>>>(
        flag, d_in[3], d_in[4], d_in[5], d_in[6],
        d_in[7], d_in[8], d_in[9], d_in[10],
        d_in[11], d_in[12], d_in[13], d_in[14], d_in[15], d_in[16],
        Wc, Vc);

    ln_in_kernel<<<dim3(2 * NB * NSQ), dim3(256), 0, stream>>>(
        flag, Q, K, Vc, Qn, Kn);

    gemm4_kernel<<<dim3(32, 8, 4), dim3(256), 0, stream>>>(
        Qn, Kn, Wc, Vc, Q1, K1, V1, R);

    vtrans_kernel<<<dim3(32, 16, 2), dim3(256), 0, stream>>>(V1, V1t);

    attn_kernel<<<dim3(NSQ / 64, NH, NB), dim3(256), 0, stream>>>(
        Q1, K1, V1t, pad_mask, R);

    ln_out_kernel<<<dim3(NB * NSQ), dim3(256), 0, stream>>>(
        flag, Q, R, Vc, d_out);
}

// Round 6
// 379.428 us; speedup vs baseline: 1.1054x; 1.1054x over previous
//
#include <hip/hip_runtime.h>
#include <stdint.h>

#define NB 2
#define NSQ 2048
#define NSK 2048
#define ND 1024
#define NH 16
#define NDH 64

typedef unsigned short u16;
typedef unsigned int u32;
typedef __bf16 bf16x8_t __attribute__((ext_vector_type(8)));
typedef float f32x4_t __attribute__((ext_vector_type(4)));
typedef u32 u32x4_t __attribute__((ext_vector_type(4)));

__device__ __forceinline__ float bf2f(u16 u) {
    union { float f; u32 i; } v; v.i = ((u32)u) << 16; return v.f;
}
__device__ __forceinline__ u16 f2bf(float x) {
    union { float f; u32 i; } v; v.f = x;
    u32 r = v.i + 0x7fffu + ((v.i >> 16) & 1u);
    return (u16)(r >> 16);
}
__device__ __forceinline__ u32 fbits(float x) {
    union { float f; u32 i; } v; v.f = x; return v.i;
}
__device__ __forceinline__ float bitsf(u32 x) {
    union { float f; u32 i; } v; v.i = x; return v.f;
}

// ---------------------------------------------------------------- dtype detect
__global__ __launch_bounds__(256) void detect_kernel(
    const u16* __restrict__ Q, int* __restrict__ flag)
{
    __shared__ int s;
    if (threadIdx.x == 0) s = 0;
    __syncthreads();
    uint2 x = ((const uint2*)Q)[threadIdx.x];
    u16 a0 = x.x & 0xffff, a1 = x.x >> 16, a2 = x.y & 0xffff, a3 = x.y >> 16;
    bool big = (((a0 >> 7) & 0xff) >= 0x8D) || (((a1 >> 7) & 0xff) >= 0x8D) ||
               (((a2 >> 7) & 0xff) >= 0x8D) || (((a3 >> 7) & 0xff) >= 0x8D);
    if (big) s = 1;
    __syncthreads();
    if (threadIdx.x == 0) *flag = s;   // 1 = f32 inputs, 0 = bf16 inputs
}

// ---------------------------------------------------------------- param canon
// canonical vec order: bq,bk,bv,bo, ln_q_g,ln_q_b, ln_kv_g,ln_kv_b, ln_f_g,ln_f_b
__global__ __launch_bounds__(256) void cvt_params_kernel(
    const int* __restrict__ flag,
    const void* __restrict__ Wq, const void* __restrict__ Wk,
    const void* __restrict__ Wv, const void* __restrict__ Wo,
    const void* __restrict__ vbq, const void* __restrict__ vbk,
    const void* __restrict__ vbv, const void* __restrict__ vbo,
    const void* __restrict__ g0, const void* __restrict__ b0,
    const void* __restrict__ g1, const void* __restrict__ b1,
    const void* __restrict__ g2, const void* __restrict__ b2,
    u16* __restrict__ Wc, u16* __restrict__ Vc)
{
    int blk = blockIdx.x;
    const void* src;
    u16* dst;
    size_t srcoff;
    if (blk < 4096) {
        int w = blk >> 10;
        src = (w == 0) ? Wq : (w == 1) ? Wk : (w == 2) ? Wv : Wo;
        srcoff = (size_t)(blk & 1023) * 1024;
        dst = Wc + (size_t)w * 1024 * 1024 + srcoff;
    } else {
        int v = blk - 4096;
        src = (v == 0) ? vbq : (v == 1) ? vbk : (v == 2) ? vbv : (v == 3) ? vbo :
              (v == 4) ? g0  : (v == 5) ? b0  : (v == 6) ? g1  : (v == 7) ? b1 :
              (v == 8) ? g2  : b2;
        srcoff = 0;
        dst = Vc + (size_t)v * 1024;
    }
    int t = threadIdx.x;
    u32 lo, hi;
    if (*flag) {
        float4 x = ((const float4*)src)[srcoff / 4 + t];
        lo = (u32)f2bf(x.x) | ((u32)f2bf(x.y) << 16);
        hi = (u32)f2bf(x.z) | ((u32)f2bf(x.w) << 16);
    } else {
        uint2 x = ((const uint2*)src)[srcoff / 4 + t];
        lo = x.x; hi = x.y;
    }
    uint2 o; o.x = lo; o.y = hi;
    ((uint2*)dst)[t] = o;
}

// ---------------------------------------------------------------- mask -> float
__global__ __launch_bounds__(256) void maskf_kernel(
    const int* __restrict__ mask, float* __restrict__ maskf)
{
    int i = blockIdx.x * 256 + threadIdx.x;
    if (i < NB * NSK) maskf[i] = (float)mask[i];
}

// ---------------------------------------------------------------- LN (inputs)
__global__ __launch_bounds__(256) void ln_in_kernel(
    const int* __restrict__ flag,
    const void* __restrict__ Q, const void* __restrict__ K,
    const u16* __restrict__ Vc,
    u16* __restrict__ Qn, u16* __restrict__ Kn)
{
    int row = blockIdx.x;
    const void* x; const u16 *g, *bb; u16* y;
    size_t roff;
    if (row < NB * NSQ) {
        x = Q; roff = (size_t)row * ND;
        g = Vc + 4 * 1024; bb = Vc + 5 * 1024;
        y = Qn + roff;
    } else {
        int r2 = row - NB * NSQ;
        x = K; roff = (size_t)r2 * ND;
        g = Vc + 6 * 1024; bb = Vc + 7 * 1024;
        y = Kn + roff;
    }
    int t = threadIdx.x;
    float v0, v1, v2, v3;
    if (*flag) {
        float4 xv = ((const float4*)x)[roff / 4 + t];
        v0 = xv.x; v1 = xv.y; v2 = xv.z; v3 = xv.w;
    } else {
        uint2 ux = ((const uint2*)x)[roff / 4 + t];
        v0 = bf2f(ux.x & 0xffff); v1 = bf2f(ux.x >> 16);
        v2 = bf2f(ux.y & 0xffff); v3 = bf2f(ux.y >> 16);
    }
    float s1 = v0 + v1 + v2 + v3;
    float s2 = v0*v0 + v1*v1 + v2*v2 + v3*v3;
#pragma unroll
    for (int off = 32; off >= 1; off >>= 1) {
        s1 += __shfl_xor(s1, off);
        s2 += __shfl_xor(s2, off);
    }
    __shared__ float r1[4], r2[4];
    int wave = t >> 6;
    if ((t & 63) == 0) { r1[wave] = s1; r2[wave] = s2; }
    __syncthreads();
    float t1 = r1[0] + r1[1] + r1[2] + r1[3];
    float t2 = r2[0] + r2[1] + r2[2] + r2[3];
    float mean = t1 * (1.0f / ND);
    float var  = t2 * (1.0f / ND) - mean * mean;
    float rstd = rsqrtf(var + 1e-5f);
    uint2 ug = ((const uint2*)g)[t];
    uint2 ub = ((const uint2*)bb)[t];
    float y0 = (v0 - mean) * rstd * bf2f(ug.x & 0xffff) + bf2f(ub.x & 0xffff);
    float y1 = (v1 - mean) * rstd * bf2f(ug.x >> 16)    + bf2f(ub.x >> 16);
    float y2 = (v2 - mean) * rstd * bf2f(ug.y & 0xffff) + bf2f(ub.y & 0xffff);
    float y3 = (v3 - mean) * rstd * bf2f(ug.y >> 16)    + bf2f(ub.y >> 16);
    uint2 o;
    o.x = (u32)f2bf(y0) | ((u32)f2bf(y1) << 16);
    o.y = (u32)f2bf(y2) | ((u32)f2bf(y3) << 16);
    ((uint2*)y)[t] = o;
}

// ---------------------------------------------------------------- fused 4x GEMM
// z=0: (Qn@Wq^T+bq)/32 -> Q1 ; z=1: Kn@Wk^T+bk -> K1
// z=2: Kn@Wv^T+bv -> V1 ; z=3: relu(Qn@Wo^T+bo) -> R
__global__ __launch_bounds__(256) void gemm4_kernel(
    const u16* __restrict__ Qn, const u16* __restrict__ Kn,
    const u16* __restrict__ Wc, const u16* __restrict__ Vc,
    u16* __restrict__ Q1, u16* __restrict__ K1, u16* __restrict__ V1,
    u16* __restrict__ R)
{
    int z = blockIdx.z;
    const u16* X    = (z == 0 || z == 3) ? Qn : Kn;
    const u16* W    = Wc + (size_t)z * 1024 * 1024;
    const u16* bias = Vc + (size_t)z * 1024;

    __shared__ u16 sA[128 * 32];
    __shared__ u16 sB[128 * 32];

    int tid  = threadIdx.x;
    int wave = tid >> 6, lane = tid & 63;
    int wm = wave >> 1, wn = wave & 1;
    int m0 = blockIdx.x * 128;
    int n0 = blockIdx.y * 128;

    f32x4_t acc[4][4];
#pragma unroll
    for (int i = 0; i < 4; ++i)
#pragma unroll
        for (int j = 0; j < 4; ++j)
            acc[i][j] = (f32x4_t){0.f, 0.f, 0.f, 0.f};

    int lrow = lane >> 2;
    int lcol = (lane & 3) * 8;

    for (int kb = 0; kb < ND / 32; ++kb) {
        __syncthreads();
        int k0 = kb * 32;
#pragma unroll
        for (int r = 0; r < 2; ++r) {
            int rowb = (r * 4 + wave) * 16;
            const u16* ga = X + (size_t)(m0 + rowb + lrow) * ND + k0 + lcol;
            const u16* gb = W + (size_t)(n0 + rowb + lrow) * ND + k0 + lcol;
            __builtin_amdgcn_global_load_lds(
                (const __attribute__((address_space(1))) u32*)ga,
                (__attribute__((address_space(3))) u32*)(sA + rowb * 32), 16, 0, 0);
            __builtin_amdgcn_global_load_lds(
                (const __attribute__((address_space(1))) u32*)gb,
                (__attribute__((address_space(3))) u32*)(sB + rowb * 32), 16, 0, 0);
        }
        __syncthreads();

        bf16x8_t af[4], bfr[4];
#pragma unroll
        for (int tm = 0; tm < 4; ++tm) {
            int rr = wm * 64 + tm * 16 + (lane & 15);
            af[tm] = *(const bf16x8_t*)(sA + rr * 32 + (lane >> 4) * 8);
        }
#pragma unroll
        for (int tn = 0; tn < 4; ++tn) {
            int rr = wn * 64 + tn * 16 + (lane & 15);
            bfr[tn] = *(const bf16x8_t*)(sB + rr * 32 + (lane >> 4) * 8);
        }
#pragma unroll
        for (int tm = 0; tm < 4; ++tm)
#pragma unroll
            for (int tn = 0; tn < 4; ++tn)
                acc[tm][tn] = __builtin_amdgcn_mfma_f32_16x16x32_bf16(
                    af[tm], bfr[tn], acc[tm][tn], 0, 0, 0);
    }

    u16* outp = (z == 0) ? Q1 : (z == 1) ? K1 : (z == 2) ? V1 : R;
#pragma unroll
    for (int tm = 0; tm < 4; ++tm) {
#pragma unroll
        for (int tn = 0; tn < 4; ++tn) {
            int n = n0 + wn * 64 + tn * 16 + (lane & 15);
            float bv_ = bf2f(bias[n]);
#pragma unroll
            for (int r = 0; r < 4; ++r) {
                int m = m0 + wm * 64 + tm * 16 + (lane >> 4) * 4 + r;
                float val = acc[tm][tn][r] + bv_;
                if (z == 0) val *= 0.03125f;
                if (z == 3) val = fmaxf(val, 0.f);
                outp[(size_t)m * ND + n] = f2bf(val);
            }
        }
    }
}

// ---------------------------------------------------------------- V transpose
// V1 [b][key][h][d] -> V1t [b][h][d][key]
__global__ __launch_bounds__(256) void vtrans_kernel(
    const u16* __restrict__ V1, u16* __restrict__ V1t)
{
    int kb = blockIdx.x;
    int h  = blockIdx.y;
    int b  = blockIdx.z;
    __shared__ u16 sT[64 * 72];
    int tid = threadIdx.x;
    {
        int row = tid >> 3, seg = tid & 7;
        const u16* gv = V1 + (size_t)(b * NSK + kb * 64 + row) * ND + h * NDH + seg * 8;
        *(uint4*)(sT + row * 72 + seg * 8)        = *(const uint4*)gv;
        *(uint4*)(sT + (row + 32) * 72 + seg * 8) = *(const uint4*)(gv + (size_t)32 * ND);
    }
    __syncthreads();
    int d = tid >> 2, sg = tid & 3;
    u16 buf[16];
#pragma unroll
    for (int i = 0; i < 8; ++i) buf[i]     = sT[(sg * 8 + i) * 72 + d];
#pragma unroll
    for (int i = 0; i < 8; ++i) buf[8 + i] = sT[((sg + 4) * 8 + i) * 72 + d];
    u16* go = V1t + ((size_t)(b * NH + h) * NDH + d) * NSK + kb * 64;
    *(uint4*)(go + sg * 8)       = *(uint4*)buf;
    *(uint4*)(go + (sg + 4) * 8) = *(uint4*)(buf + 8);
}

// ---------------------------------------------------------------- flash attention
// S^T = K.Q^T; LDS-staged K/V with register prefetch, BK=128 (2 barriers per
// 128 keys). No-max softmax (scores LN-bounded): p = exp(s)*mask, O/l at end.
__global__ __launch_bounds__(256, 4) void attn_kernel(
    const u16* __restrict__ Q1, const u16* __restrict__ K1,
    const u16* __restrict__ V1t, const float* __restrict__ maskf,
    u16* __restrict__ R)
{
    int q0 = blockIdx.x * 64;
    int h  = blockIdx.y;
    int b  = blockIdx.z;

    __shared__ u16 sK[128 * 72];    // [key][dh]
    __shared__ u16 sVt[64 * 136];   // [d][key 0..127]

    int tid  = threadIdx.x;
    int wave = tid >> 6, lane = tid & 63;
    int quad = lane >> 4, l4 = lane & 15;

    // Q B-operand fragments (once per block)
    bf16x8_t qf[2];
    {
        const u16* qp = Q1 + (size_t)(b * NSQ + q0 + wave * 16 + l4) * ND + h * NDH;
        qf[0] = *(const bf16x8_t*)(qp + quad * 8);
        qf[1] = *(const bf16x8_t*)(qp + 32 + quad * 8);
    }

    const u16* kbase = K1 + (size_t)b * NSK * ND + h * NDH;
    const u16* vbase = V1t + (size_t)(b * NH + h) * NDH * NSK;
    const float* mbase = maskf + b * NSK;

    // staging thread mapping
    int krow = tid >> 3, kseg = tid & 7;          // K: rows 0..31 (+32/64/96), 8 segs
    int vd = tid >> 2, vc4 = tid & 3;             // V: d 0..63, 4 chunk-cols

    uint4 rk[4], rv[4];
    {
        const u16* gk = kbase + (size_t)krow * ND + kseg * 8;
#pragma unroll
        for (int i = 0; i < 4; ++i)
            rk[i] = *(const uint4*)(gk + (size_t)(i * 32) * ND);
        const u16* gv = vbase + (size_t)vd * NSK;
#pragma unroll
        for (int i = 0; i < 4; ++i)
            rv[i] = *(const uint4*)(gv + (vc4 + 4 * i) * 8);
    }

    float l_run = 0.f;               // per-lane: q = l4
    f32x4_t acc_o[4];                // O^T C-layout: d = T*16+quad*4+r, q = l4
#pragma unroll
    for (int T = 0; T < 4; ++T) acc_o[T] = (f32x4_t){0.f, 0.f, 0.f, 0.f};

    int srcA = (quad & 1) * 32 + l4;
    int srcB = srcA + 16;
    bool hi = lane >= 32;

    for (int kb = 0; kb < NSK / 128; ++kb) {
        // store prefetched tile -> LDS
#pragma unroll
        for (int i = 0; i < 4; ++i)
            *(uint4*)(sK + (krow + i * 32) * 72 + kseg * 8) = rk[i];
#pragma unroll
        for (int i = 0; i < 4; ++i)
            *(uint4*)(sVt + vd * 136 + (vc4 + 4 * i) * 8) = rv[i];
        __syncthreads();

        // issue next-tile global loads (overlap with compute)
        if (kb + 1 < NSK / 128) {
            int key1 = (kb + 1) * 128;
            const u16* gk = kbase + (size_t)(key1 + krow) * ND + kseg * 8;
#pragma unroll
            for (int i = 0; i < 4; ++i)
                rk[i] = *(const uint4*)(gk + (size_t)(i * 32) * ND);
            const u16* gv = vbase + (size_t)vd * NSK + key1;
#pragma unroll
            for (int i = 0; i < 4; ++i)
                rv[i] = *(const uint4*)(gv + (vc4 + 4 * i) * 8);
        }

#pragma unroll
        for (int half = 0; half < 2; ++half) {
            int keyh = half * 64;

            // S^T = K @ Q^T : C-layout key = tm*16+quad*4+r, col q = l4
            f32x4_t accs[4];
#pragma unroll
            for (int tm = 0; tm < 4; ++tm) accs[tm] = (f32x4_t){0.f, 0.f, 0.f, 0.f};
#pragma unroll
            for (int kk = 0; kk < 2; ++kk)
#pragma unroll
                for (int tm = 0; tm < 4; ++tm) {
                    bf16x8_t kf = *(const bf16x8_t*)(sK +
                        (keyh + tm * 16 + l4) * 72 + kk * 32 + quad * 8);
                    accs[tm] = __builtin_amdgcn_mfma_f32_16x16x32_bf16(
                        kf, qf[kk], accs[tm], 0, 0, 0);
                }

            f32x4_t mv[4];
#pragma unroll
            for (int tm = 0; tm < 4; ++tm)
                mv[tm] = *(const f32x4_t*)(mbase + kb * 128 + keyh + tm * 16 + quad * 4);

            // no-max softmax: p = exp(s) * mask
            float lsum = 0.f;
            u32 pk[4][2];
#pragma unroll
            for (int tm = 0; tm < 4; ++tm) {
                u32 pb[4];
#pragma unroll
                for (int r = 0; r < 4; ++r) {
                    float p = __expf(accs[tm][r]) * mv[tm][r];
                    u32 tb = fbits(p) & 0xffff0000u;
                    lsum += bitsf(tb);
                    pb[r] = tb;
                }
                pk[tm][0] = (pb[0] >> 16) | pb[1];
                pk[tm][1] = (pb[2] >> 16) | pb[3];
            }
            lsum += __shfl_xor(lsum, 16);
            lsum += __shfl_xor(lsum, 32);
            l_run += lsum;

#pragma unroll
            for (int kk = 0; kk < 2; ++kk) {
                u32 a0 = __shfl((int)pk[kk * 2][0], srcA), a1 = __shfl((int)pk[kk * 2][1], srcA);
                u32 b0 = __shfl((int)pk[kk * 2 + 1][0], srcA), b1 = __shfl((int)pk[kk * 2 + 1][1], srcA);
                u32 c0 = __shfl((int)pk[kk * 2][0], srcB), c1 = __shfl((int)pk[kk * 2][1], srcB);
                u32 d0 = __shfl((int)pk[kk * 2 + 1][0], srcB), d1 = __shfl((int)pk[kk * 2 + 1][1], srcB);
                u32x4_t pr;
                pr.x = hi ? b0 : a0;
                pr.y = hi ? b1 : a1;
                pr.z = hi ? d0 : c0;
                pr.w = hi ? d1 : c1;
                bf16x8_t pf = __builtin_bit_cast(bf16x8_t, pr);
#pragma unroll
                for (int T = 0; T < 4; ++T) {
                    bf16x8_t vf = *(const bf16x8_t*)(sVt +
                        (T * 16 + l4) * 136 + keyh + kk * 32 + quad * 8);
                    acc_o[T] = __builtin_amdgcn_mfma_f32_16x16x32_bf16(
                        vf, pf, acc_o[T], 0, 0, 0);
                }
            }
        }
        __syncthreads();
    }

    // epilogue: O[q][d] = acc_o / l ; R += O1 (uint2 RMW)
    float inv = l_run > 0.f ? 1.f / l_run : 0.f;
    u16* rp = R + (size_t)(b * NSQ + q0 + wave * 16 + l4) * ND + h * NDH;
#pragma unroll
    for (int T = 0; T < 4; ++T) {
        u16* p = rp + T * 16 + quad * 4;
        uint2 o2 = *(const uint2*)p;
        float e0 = acc_o[T][0] * inv + bf2f(o2.x & 0xffff);
        float e1 = acc_o[T][1] * inv + bf2f(o2.x >> 16);
        float e2 = acc_o[T][2] * inv + bf2f(o2.y & 0xffff);
        float e3 = acc_o[T][3] * inv + bf2f(o2.y >> 16);
        uint2 on;
        on.x = (u32)f2bf(e0) | ((u32)f2bf(e1) << 16);
        on.y = (u32)f2bf(e2) | ((u32)f2bf(e3) << 16);
        *(uint2*)p = on;
    }
}

// ---------------------------------------------------------------- final LN
__global__ __launch_bounds__(256) void ln_out_kernel(
    const int* __restrict__ flag,
    const void* __restrict__ Q, const u16* __restrict__ R,
    const u16* __restrict__ Vc, void* __restrict__ out)
{
    int row = blockIdx.x;
    size_t roff = (size_t)row * ND;
    int t = threadIdx.x;
    int f = *flag;
    float v0, v1, v2, v3;
    uint2 ur = ((const uint2*)(R + roff))[t];
    if (f) {
        float4 xq = ((const float4*)Q)[roff / 4 + t];
        v0 = xq.x; v1 = xq.y; v2 = xq.z; v3 = xq.w;
    } else {
        uint2 uq = ((const uint2*)Q)[roff / 4 + t];
        v0 = bf2f(uq.x & 0xffff); v1 = bf2f(uq.x >> 16);
        v2 = bf2f(uq.y & 0xffff); v3 = bf2f(uq.y >> 16);
    }
    v0 += bf2f(ur.x & 0xffff); v1 += bf2f(ur.x >> 16);
    v2 += bf2f(ur.y & 0xffff); v3 += bf2f(ur.y >> 16);
    float s1 = v0 + v1 + v2 + v3;
    float s2 = v0*v0 + v1*v1 + v2*v2 + v3*v3;
#pragma unroll
    for (int off = 32; off >= 1; off >>= 1) {
        s1 += __shfl_xor(s1, off);
        s2 += __shfl_xor(s2, off);
    }
    __shared__ float r1[4], r2[4];
    int wave = t >> 6;
    if ((t & 63) == 0) { r1[wave] = s1; r2[wave] = s2; }
    __syncthreads();
    float t1 = r1[0] + r1[1] + r1[2] + r1[3];
    float t2 = r2[0] + r2[1] + r2[2] + r2[3];
    float mean = t1 * (1.0f / ND);
    float var  = t2 * (1.0f / ND) - mean * mean;
    float rstd = rsqrtf(var + 1e-5f);
    const u16* g  = Vc + 8 * 1024;
    const u16* bb = Vc + 9 * 1024;
    uint2 ug = ((const uint2*)g)[t];
    uint2 ub = ((const uint2*)bb)[t];
    float y0 = (v0 - mean) * rstd * bf2f(ug.x & 0xffff) + bf2f(ub.x & 0xffff);
    float y1 = (v1 - mean) * rstd * bf2f(ug.x >> 16)    + bf2f(ub.x >> 16);
    float y2 = (v2 - mean) * rstd * bf2f(ug.y & 0xffff) + bf2f(ub.y & 0xffff);
    float y3 = (v3 - mean) * rstd * bf2f(ug.y >> 16)    + bf2f(ub.y >> 16);
    if (f) {
        float4 o; o.x = y0; o.y = y1; o.z = y2; o.w = y3;
        ((float4*)out)[roff / 4 + t] = o;
    } else {
        uint2 o;
        o.x = (u32)f2bf(y0) | ((u32)f2bf(y1) << 16);
        o.y = (u32)f2bf(y2) | ((u32)f2bf(y3) << 16);
        ((uint2*)out)[roff / 4 + t] = o;
    }
}

// ---------------------------------------------------------------- launch
extern "C" void kernel_launch(void* const* d_in, const int* in_sizes, int n_in,
                              void* d_out, int out_size, void* d_ws, size_t ws_size,
                              hipStream_t stream) {
    const void* Q        = d_in[0];
    const void* K        = d_in[1];
    const int* pad_mask  = (const int*)d_in[2];

    const size_t NEL = (size_t)NB * NSQ * ND;   // 4,194,304
    int* flag = (int*)d_ws;
    u16* base = (u16*)d_ws + 128;
    u16* Qn  = base;
    u16* Kn  = Qn + NEL;
    u16* Q1  = Kn + NEL;
    u16* K1  = Q1 + NEL;
    u16* V1  = K1 + NEL;
    u16* R   = V1 + NEL;
    u16* Wc  = R + NEL;
    u16* Vc  = Wc + (size_t)4 * 1024 * 1024;
    float* maskf = (float*)(Vc + 10 * 1024);
    u16* V1t = Qn;                               // aliases Qn (dead after gemm4)

    detect_kernel<<<dim3(1), dim3(256), 0, stream>>>((const u16*)Q, flag);

    cvt_params_kernel<<<dim3(4106), dim3(256), 0, stream>>>(
        flag, d_in[3], d_in[4], d_in[5], d_in[6],
        d_in[7], d_in[8], d_in[9], d_in[10],
        d_in[11], d_in[12], d_in[13], d_in[14], d_in[15], d_in[16],
        Wc, Vc);

    maskf_kernel<<<dim3(16), dim3(256), 0, stream>>>(pad_mask, maskf);

    ln_in_kernel<<<dim3(2 * NB * NSQ), dim3(256), 0, stream>>>(
        flag, Q, K, Vc, Qn, Kn);

    gemm4_kernel<<<dim3(32, 8, 4), dim3(256), 0, stream>>>(
        Qn, Kn, Wc, Vc, Q1, K1, V1, R);

    vtrans_kernel<<<dim3(32, 16, 2), dim3(256), 0, stream>>>(V1, V1t);

    attn_kernel<<<dim3(NSQ / 64, NH, NB), dim3(256), 0, stream>>>(
        Q1, K1, V1t, maskf, R);

    ln_out_kernel<<<dim3(NB * NSQ), dim3(256), 0, stream>>>(
        flag, Q, R, Vc, d_out);
}

// Round 7
// 268.048 us; speedup vs baseline: 1.5647x; 1.4155x over previous
//
#include <hip/hip_runtime.h>
#include <stdint.h>

#define NB 2
#define NSQ 2048
#define NSK 2048
#define ND 1024
#define NH 16
#define NDH 64

typedef unsigned short u16;
typedef unsigned int u32;
typedef __bf16 bf16x8_t __attribute__((ext_vector_type(8)));
typedef float f32x4_t __attribute__((ext_vector_type(4)));
typedef u32 u32x4_t __attribute__((ext_vector_type(4)));

#define AS1 __attribute__((address_space(1)))
#define AS3 __attribute__((address_space(3)))

__device__ __forceinline__ float bf2f(u16 u) {
    union { float f; u32 i; } v; v.i = ((u32)u) << 16; return v.f;
}
__device__ __forceinline__ u16 f2bf(float x) {
    union { float f; u32 i; } v; v.f = x;
    u32 r = v.i + 0x7fffu + ((v.i >> 16) & 1u);
    return (u16)(r >> 16);
}
__device__ __forceinline__ u32 fbits(float x) {
    union { float f; u32 i; } v; v.f = x; return v.i;
}
__device__ __forceinline__ float bitsf(u32 x) {
    union { float f; u32 i; } v; v.i = x; return v.f;
}

// ---------------------------------------------------------------- dtype detect
__global__ __launch_bounds__(256) void detect_kernel(
    const u16* __restrict__ Q, int* __restrict__ flag)
{
    __shared__ int s;
    if (threadIdx.x == 0) s = 0;
    __syncthreads();
    uint2 x = ((const uint2*)Q)[threadIdx.x];
    u16 a0 = x.x & 0xffff, a1 = x.x >> 16, a2 = x.y & 0xffff, a3 = x.y >> 16;
    bool big = (((a0 >> 7) & 0xff) >= 0x8D) || (((a1 >> 7) & 0xff) >= 0x8D) ||
               (((a2 >> 7) & 0xff) >= 0x8D) || (((a3 >> 7) & 0xff) >= 0x8D);
    if (big) s = 1;
    __syncthreads();
    if (threadIdx.x == 0) *flag = s;   // 1 = f32 inputs, 0 = bf16 inputs
}

// ---------------------------------------------------------------- param canon
// canonical vec order: bq,bk,bv,bo, ln_q_g,ln_q_b, ln_kv_g,ln_kv_b, ln_f_g,ln_f_b
__global__ __launch_bounds__(256) void cvt_params_kernel(
    const int* __restrict__ flag,
    const void* __restrict__ Wq, const void* __restrict__ Wk,
    const void* __restrict__ Wv, const void* __restrict__ Wo,
    const void* __restrict__ vbq, const void* __restrict__ vbk,
    const void* __restrict__ vbv, const void* __restrict__ vbo,
    const void* __restrict__ g0, const void* __restrict__ b0,
    const void* __restrict__ g1, const void* __restrict__ b1,
    const void* __restrict__ g2, const void* __restrict__ b2,
    u16* __restrict__ Wc, u16* __restrict__ Vc)
{
    int blk = blockIdx.x;
    const void* src;
    u16* dst;
    size_t srcoff;
    if (blk < 4096) {
        int w = blk >> 10;
        src = (w == 0) ? Wq : (w == 1) ? Wk : (w == 2) ? Wv : Wo;
        srcoff = (size_t)(blk & 1023) * 1024;
        dst = Wc + (size_t)w * 1024 * 1024 + srcoff;
    } else {
        int v = blk - 4096;
        src = (v == 0) ? vbq : (v == 1) ? vbk : (v == 2) ? vbv : (v == 3) ? vbo :
              (v == 4) ? g0  : (v == 5) ? b0  : (v == 6) ? g1  : (v == 7) ? b1 :
              (v == 8) ? g2  : b2;
        srcoff = 0;
        dst = Vc + (size_t)v * 1024;
    }
    int t = threadIdx.x;
    u32 lo, hi;
    if (*flag) {
        float4 x = ((const float4*)src)[srcoff / 4 + t];
        lo = (u32)f2bf(x.x) | ((u32)f2bf(x.y) << 16);
        hi = (u32)f2bf(x.z) | ((u32)f2bf(x.w) << 16);
    } else {
        uint2 x = ((const uint2*)src)[srcoff / 4 + t];
        lo = x.x; hi = x.y;
    }
    uint2 o; o.x = lo; o.y = hi;
    ((uint2*)dst)[t] = o;
}

// ---------------------------------------------------------------- mask -> float
__global__ __launch_bounds__(256) void maskf_kernel(
    const int* __restrict__ mask, float* __restrict__ maskf)
{
    int i = blockIdx.x * 256 + threadIdx.x;
    if (i < NB * NSK) maskf[i] = (float)mask[i];
}

// ---------------------------------------------------------------- LN (inputs)
__global__ __launch_bounds__(256) void ln_in_kernel(
    const int* __restrict__ flag,
    const void* __restrict__ Q, const void* __restrict__ K,
    const u16* __restrict__ Vc,
    u16* __restrict__ Qn, u16* __restrict__ Kn)
{
    int row = blockIdx.x;
    const void* x; const u16 *g, *bb; u16* y;
    size_t roff;
    if (row < NB * NSQ) {
        x = Q; roff = (size_t)row * ND;
        g = Vc + 4 * 1024; bb = Vc + 5 * 1024;
        y = Qn + roff;
    } else {
        int r2 = row - NB * NSQ;
        x = K; roff = (size_t)r2 * ND;
        g = Vc + 6 * 1024; bb = Vc + 7 * 1024;
        y = Kn + roff;
    }
    int t = threadIdx.x;
    float v0, v1, v2, v3;
    if (*flag) {
        float4 xv = ((const float4*)x)[roff / 4 + t];
        v0 = xv.x; v1 = xv.y; v2 = xv.z; v3 = xv.w;
    } else {
        uint2 ux = ((const uint2*)x)[roff / 4 + t];
        v0 = bf2f(ux.x & 0xffff); v1 = bf2f(ux.x >> 16);
        v2 = bf2f(ux.y & 0xffff); v3 = bf2f(ux.y >> 16);
    }
    float s1 = v0 + v1 + v2 + v3;
    float s2 = v0*v0 + v1*v1 + v2*v2 + v3*v3;
#pragma unroll
    for (int off = 32; off >= 1; off >>= 1) {
        s1 += __shfl_xor(s1, off);
        s2 += __shfl_xor(s2, off);
    }
    __shared__ float r1[4], r2[4];
    int wave = t >> 6;
    if ((t & 63) == 0) { r1[wave] = s1; r2[wave] = s2; }
    __syncthreads();
    float t1 = r1[0] + r1[1] + r1[2] + r1[3];
    float t2 = r2[0] + r2[1] + r2[2] + r2[3];
    float mean = t1 * (1.0f / ND);
    float var  = t2 * (1.0f / ND) - mean * mean;
    float rstd = rsqrtf(var + 1e-5f);
    uint2 ug = ((const uint2*)g)[t];
    uint2 ub = ((const uint2*)bb)[t];
    float y0 = (v0 - mean) * rstd * bf2f(ug.x & 0xffff) + bf2f(ub.x & 0xffff);
    float y1 = (v1 - mean) * rstd * bf2f(ug.x >> 16)    + bf2f(ub.x >> 16);
    float y2 = (v2 - mean) * rstd * bf2f(ug.y & 0xffff) + bf2f(ub.y & 0xffff);
    float y3 = (v3 - mean) * rstd * bf2f(ug.y >> 16)    + bf2f(ub.y >> 16);
    uint2 o;
    o.x = (u32)f2bf(y0) | ((u32)f2bf(y1) << 16);
    o.y = (u32)f2bf(y2) | ((u32)f2bf(y3) << 16);
    ((uint2*)y)[t] = o;
}

// ---------------------------------------------------------------- fused 4x GEMM
// z=0: (Qn@Wq^T+bq)*log2e/32 -> Q1 (exp2 + 1/sqrt(D) folded)
// z=1: Kn@Wk^T+bk -> K1 ; z=2: Kn@Wv^T+bv -> V1 ; z=3: relu(Qn@Wo^T+bo) -> R
__global__ __launch_bounds__(256) void gemm4_kernel(
    const u16* __restrict__ Qn, const u16* __restrict__ Kn,
    const u16* __restrict__ Wc, const u16* __restrict__ Vc,
    u16* __restrict__ Q1, u16* __restrict__ K1, u16* __restrict__ V1,
    u16* __restrict__ R)
{
    int z = blockIdx.z;
    const u16* X    = (z == 0 || z == 3) ? Qn : Kn;
    const u16* W    = Wc + (size_t)z * 1024 * 1024;
    const u16* bias = Vc + (size_t)z * 1024;

    __shared__ u16 sA[128 * 32];
    __shared__ u16 sB[128 * 32];

    int tid  = threadIdx.x;
    int wave = tid >> 6, lane = tid & 63;
    int wm = wave >> 1, wn = wave & 1;
    int m0 = blockIdx.x * 128;
    int n0 = blockIdx.y * 128;

    f32x4_t acc[4][4];
#pragma unroll
    for (int i = 0; i < 4; ++i)
#pragma unroll
        for (int j = 0; j < 4; ++j)
            acc[i][j] = (f32x4_t){0.f, 0.f, 0.f, 0.f};

    int lrow = lane >> 2;
    int lcol = (lane & 3) * 8;

    for (int kb = 0; kb < ND / 32; ++kb) {
        __syncthreads();
        int k0 = kb * 32;
#pragma unroll
        for (int r = 0; r < 2; ++r) {
            int rowb = (r * 4 + wave) * 16;
            const u16* ga = X + (size_t)(m0 + rowb + lrow) * ND + k0 + lcol;
            const u16* gb = W + (size_t)(n0 + rowb + lrow) * ND + k0 + lcol;
            __builtin_amdgcn_global_load_lds(
                (const AS1 u32*)ga, (AS3 u32*)(sA + rowb * 32), 16, 0, 0);
            __builtin_amdgcn_global_load_lds(
                (const AS1 u32*)gb, (AS3 u32*)(sB + rowb * 32), 16, 0, 0);
        }
        __syncthreads();

        bf16x8_t af[4], bfr[4];
#pragma unroll
        for (int tm = 0; tm < 4; ++tm) {
            int rr = wm * 64 + tm * 16 + (lane & 15);
            af[tm] = *(const bf16x8_t*)(sA + rr * 32 + (lane >> 4) * 8);
        }
#pragma unroll
        for (int tn = 0; tn < 4; ++tn) {
            int rr = wn * 64 + tn * 16 + (lane & 15);
            bfr[tn] = *(const bf16x8_t*)(sB + rr * 32 + (lane >> 4) * 8);
        }
#pragma unroll
        for (int tm = 0; tm < 4; ++tm)
#pragma unroll
            for (int tn = 0; tn < 4; ++tn)
                acc[tm][tn] = __builtin_amdgcn_mfma_f32_16x16x32_bf16(
                    af[tm], bfr[tn], acc[tm][tn], 0, 0, 0);
    }

    u16* outp = (z == 0) ? Q1 : (z == 1) ? K1 : (z == 2) ? V1 : R;
#pragma unroll
    for (int tm = 0; tm < 4; ++tm) {
#pragma unroll
        for (int tn = 0; tn < 4; ++tn) {
            int n = n0 + wn * 64 + tn * 16 + (lane & 15);
            float bv_ = bf2f(bias[n]);
#pragma unroll
            for (int r = 0; r < 4; ++r) {
                int m = m0 + wm * 64 + tm * 16 + (lane >> 4) * 4 + r;
                float val = acc[tm][tn][r] + bv_;
                if (z == 0) val *= 0.045105964f;   // (1/32) * log2(e)
                if (z == 3) val = fmaxf(val, 0.f);
                outp[(size_t)m * ND + n] = f2bf(val);
            }
        }
    }
}

// ---------------------------------------------------------------- V transpose
// V1 [b][key][h][d] -> V1t [b][h][d][key]
__global__ __launch_bounds__(256) void vtrans_kernel(
    const u16* __restrict__ V1, u16* __restrict__ V1t)
{
    int kb = blockIdx.x;
    int h  = blockIdx.y;
    int b  = blockIdx.z;
    __shared__ u16 sT[64 * 72];
    int tid = threadIdx.x;
    {
        int row = tid >> 3, seg = tid & 7;
        const u16* gv = V1 + (size_t)(b * NSK + kb * 64 + row) * ND + h * NDH + seg * 8;
        *(uint4*)(sT + row * 72 + seg * 8)        = *(const uint4*)gv;
        *(uint4*)(sT + (row + 32) * 72 + seg * 8) = *(const uint4*)(gv + (size_t)32 * ND);
    }
    __syncthreads();
    int d = tid >> 2, sg = tid & 3;
    u16 buf[16];
#pragma unroll
    for (int i = 0; i < 8; ++i) buf[i]     = sT[(sg * 8 + i) * 72 + d];
#pragma unroll
    for (int i = 0; i < 8; ++i) buf[8 + i] = sT[((sg + 4) * 8 + i) * 72 + d];
    u16* go = V1t + ((size_t)(b * NH + h) * NDH + d) * NSK + kb * 64;
    *(uint4*)(go + sg * 8)       = *(uint4*)buf;
    *(uint4*)(go + (sg + 4) * 8) = *(uint4*)(buf + 8);
}

// ---------------------------------------------------------------- flash attention
// S^T = K.Q^T; K/V staged via global_load_lds into DOUBLE-BUFFERED swizzled
// LDS (seg' = seg ^ (row&7)); 1 barrier per 64-key iter; no VGPRs held across
// barriers (no spill). No-max softmax: p = exp2(s)*mask (Q1 pre-scaled).
__global__ __launch_bounds__(256, 4) void attn_kernel(
    const u16* __restrict__ Q1, const u16* __restrict__ K1,
    const u16* __restrict__ V1t, const float* __restrict__ maskf,
    u16* __restrict__ R)
{
    int q0 = blockIdx.x * 64;
    int h  = blockIdx.y;
    int b  = blockIdx.z;

    __shared__ u16 sK[2][64 * 64];   // [key][seg^(key&7)] swizzled, 8 KB each
    __shared__ u16 sV[2][64 * 64];   // [d][keyseg^(d&7)] swizzled

    int tid  = threadIdx.x;
    int wave = tid >> 6, lane = tid & 63;
    int quad = lane >> 4, l4 = lane & 15;
    int lk = lane >> 3, ls = lane & 7;       // DMA: local row, phys seg
    int gseg = ls ^ lk;                      // global seg feeding phys seg ls

    // Q B-operand fragments (once per block)
    bf16x8_t qf[2];
    {
        const u16* qp = Q1 + (size_t)(b * NSQ + q0 + wave * 16 + l4) * ND + h * NDH;
        qf[0] = *(const bf16x8_t*)(qp + quad * 8);
        qf[1] = *(const bf16x8_t*)(qp + 32 + quad * 8);
    }

    const u16* kbase = K1 + (size_t)b * NSK * ND + h * NDH;
    const u16* vbase = V1t + (size_t)(b * NH + h) * NDH * NSK;
    const float* mbase = maskf + b * NSK;

    // per-lane DMA global pointers (tile-invariant parts)
    const u16* gk = kbase + (size_t)(wave * 16 + lk) * ND + gseg * 8;
    const u16* gv = vbase + (size_t)(wave * 16 + lk) * NSK + gseg * 8;

    float l_run = 0.f;               // per-lane: q = l4
    f32x4_t acc_o[4];                // O^T C-layout: d = T*16+quad*4+r, q = l4
#pragma unroll
    for (int T = 0; T < 4; ++T) acc_o[T] = (f32x4_t){0.f, 0.f, 0.f, 0.f};

    int srcA = (quad & 1) * 32 + l4;
    int srcB = srcA + 16;
    bool hi = lane >= 32;

    // stage tile 0 into buffer 0
#pragma unroll
    for (int j = 0; j < 2; ++j) {
        __builtin_amdgcn_global_load_lds(
            (const AS1 u32*)(gk + (size_t)(j * 8) * ND),
            (AS3 u32*)(&sK[0][(wave * 16 + j * 8) * 64]), 16, 0, 0);
        __builtin_amdgcn_global_load_lds(
            (const AS1 u32*)(gv + (size_t)(j * 8) * NSK),
            (AS3 u32*)(&sV[0][(wave * 16 + j * 8) * 64]), 16, 0, 0);
    }

    for (int kb = 0; kb < NSK / 64; ++kb) {
        __syncthreads();   // drains DMA(kb) [vmcnt(0) auto]; readers of kb-1 done

        if (kb + 1 < NSK / 64) {
            int key1 = (kb + 1) * 64;
            int bi = (kb + 1) & 1;
#pragma unroll
            for (int j = 0; j < 2; ++j) {
                __builtin_amdgcn_global_load_lds(
                    (const AS1 u32*)(gk + (size_t)(key1 + j * 8) * ND),
                    (AS3 u32*)(&sK[bi][(wave * 16 + j * 8) * 64]), 16, 0, 0);
                __builtin_amdgcn_global_load_lds(
                    (const AS1 u32*)(gv + (size_t)(j * 8) * NSK + key1),
                    (AS3 u32*)(&sV[bi][(wave * 16 + j * 8) * 64]), 16, 0, 0);
            }
        }

        const u16* kt = sK[kb & 1];
        const u16* vt = sV[kb & 1];

        // S^T = K @ Q^T : C-layout key = tm*16+quad*4+r, col q = l4
        f32x4_t accs[4];
#pragma unroll
        for (int tm = 0; tm < 4; ++tm) accs[tm] = (f32x4_t){0.f, 0.f, 0.f, 0.f};
#pragma unroll
        for (int kk = 0; kk < 2; ++kk)
#pragma unroll
            for (int tm = 0; tm < 4; ++tm) {
                int s = kk * 4 + quad;
                bf16x8_t kf = *(const bf16x8_t*)(kt +
                    (tm * 16 + l4) * 64 + (s ^ (l4 & 7)) * 8);
                accs[tm] = __builtin_amdgcn_mfma_f32_16x16x32_bf16(
                    kf, qf[kk], accs[tm], 0, 0, 0);
            }

        f32x4_t mv[4];
#pragma unroll
        for (int tm = 0; tm < 4; ++tm)
            mv[tm] = *(const f32x4_t*)(mbase + kb * 64 + tm * 16 + quad * 4);

        // no-max softmax: p = exp2(s_pre-scaled) * mask
        float lsum = 0.f;
        u32 pk[4][2];
#pragma unroll
        for (int tm = 0; tm < 4; ++tm) {
            u32 pb[4];
#pragma unroll
            for (int r = 0; r < 4; ++r) {
                float p = exp2f(accs[tm][r]) * mv[tm][r];
                u32 tb = fbits(p) & 0xffff0000u;
                lsum += bitsf(tb);
                pb[r] = tb;
            }
            pk[tm][0] = (pb[0] >> 16) | pb[1];
            pk[tm][1] = (pb[2] >> 16) | pb[3];
        }
        lsum += __shfl_xor(lsum, 16);
        lsum += __shfl_xor(lsum, 32);
        l_run += lsum;

        // O^T += V^T @ P^T (P^T B-fragment built via cross-lane shuffles)
#pragma unroll
        for (int kk = 0; kk < 2; ++kk) {
            u32 a0 = __shfl((int)pk[kk * 2][0], srcA), a1 = __shfl((int)pk[kk * 2][1], srcA);
            u32 b0 = __shfl((int)pk[kk * 2 + 1][0], srcA), b1 = __shfl((int)pk[kk * 2 + 1][1], srcA);
            u32 c0 = __shfl((int)pk[kk * 2][0], srcB), c1 = __shfl((int)pk[kk * 2][1], srcB);
            u32 d0 = __shfl((int)pk[kk * 2 + 1][0], srcB), d1 = __shfl((int)pk[kk * 2 + 1][1], srcB);
            u32x4_t pr;
            pr.x = hi ? b0 : a0;
            pr.y = hi ? b1 : a1;
            pr.z = hi ? d0 : c0;
            pr.w = hi ? d1 : c1;
            bf16x8_t pf = __builtin_bit_cast(bf16x8_t, pr);
#pragma unroll
            for (int T = 0; T < 4; ++T) {
                int s = kk * 4 + quad;
                bf16x8_t vf = *(const bf16x8_t*)(vt +
                    (T * 16 + l4) * 64 + (s ^ (l4 & 7)) * 8);
                acc_o[T] = __builtin_amdgcn_mfma_f32_16x16x32_bf16(
                    vf, pf, acc_o[T], 0, 0, 0);
            }
        }
    }

    // epilogue: O[q][d] = acc_o / l ; R += O1 (uint2 RMW)
    float inv = l_run > 0.f ? 1.f / l_run : 0.f;
    u16* rp = R + (size_t)(b * NSQ + q0 + wave * 16 + l4) * ND + h * NDH;
#pragma unroll
    for (int T = 0; T < 4; ++T) {
        u16* p = rp + T * 16 + quad * 4;
        uint2 o2 = *(const uint2*)p;
        float e0 = acc_o[T][0] * inv + bf2f(o2.x & 0xffff);
        float e1 = acc_o[T][1] * inv + bf2f(o2.x >> 16);
        float e2 = acc_o[T][2] * inv + bf2f(o2.y & 0xffff);
        float e3 = acc_o[T][3] * inv + bf2f(o2.y >> 16);
        uint2 on;
        on.x = (u32)f2bf(e0) | ((u32)f2bf(e1) << 16);
        on.y = (u32)f2bf(e2) | ((u32)f2bf(e3) << 16);
        *(uint2*)p = on;
    }
}

// ---------------------------------------------------------------- final LN
__global__ __launch_bounds__(256) void ln_out_kernel(
    const int* __restrict__ flag,
    const void* __restrict__ Q, const u16* __restrict__ R,
    const u16* __restrict__ Vc, void* __restrict__ out)
{
    int row = blockIdx.x;
    size_t roff = (size_t)row * ND;
    int t = threadIdx.x;
    int f = *flag;
    float v0, v1, v2, v3;
    uint2 ur = ((const uint2*)(R + roff))[t];
    if (f) {
        float4 xq = ((const float4*)Q)[roff / 4 + t];
        v0 = xq.x; v1 = xq.y; v2 = xq.z; v3 = xq.w;
    } else {
        uint2 uq = ((const uint2*)Q)[roff / 4 + t];
        v0 = bf2f(uq.x & 0xffff); v1 = bf2f(uq.x >> 16);
        v2 = bf2f(uq.y & 0xffff); v3 = bf2f(uq.y >> 16);
    }
    v0 += bf2f(ur.x & 0xffff); v1 += bf2f(ur.x >> 16);
    v2 += bf2f(ur.y & 0xffff); v3 += bf2f(ur.y >> 16);
    float s1 = v0 + v1 + v2 + v3;
    float s2 = v0*v0 + v1*v1 + v2*v2 + v3*v3;
#pragma unroll
    for (int off = 32; off >= 1; off >>= 1) {
        s1 += __shfl_xor(s1, off);
        s2 += __shfl_xor(s2, off);
    }
    __shared__ float r1[4], r2[4];
    int wave = t >> 6;
    if ((t & 63) == 0) { r1[wave] = s1; r2[wave] = s2; }
    __syncthreads();
    float t1 = r1[0] + r1[1] + r1[2] + r1[3];
    float t2 = r2[0] + r2[1] + r2[2] + r2[3];
    float mean = t1 * (1.0f / ND);
    float var  = t2 * (1.0f / ND) - mean * mean;
    float rstd = rsqrtf(var + 1e-5f);
    const u16* g  = Vc + 8 * 1024;
    const u16* bb = Vc + 9 * 1024;
    uint2 ug = ((const uint2*)g)[t];
    uint2 ub = ((const uint2*)bb)[t];
    float y0 = (v0 - mean) * rstd * bf2f(ug.x & 0xffff) + bf2f(ub.x & 0xffff);
    float y1 = (v1 - mean) * rstd * bf2f(ug.x >> 16)    + bf2f(ub.x >> 16);
    float y2 = (v2 - mean) * rstd * bf2f(ug.y & 0xffff) + bf2f(ub.y & 0xffff);
    float y3 = (v3 - mean) * rstd * bf2f(ug.y >> 16)    + bf2f(ub.y >> 16);
    if (f) {
        float4 o; o.x = y0; o.y = y1; o.z = y2; o.w = y3;
        ((float4*)out)[roff / 4 + t] = o;
    } else {
        uint2 o;
        o.x = (u32)f2bf(y0) | ((u32)f2bf(y1) << 16);
        o.y = (u32)f2bf(y2) | ((u32)f2bf(y3) << 16);
        ((uint2*)out)[roff / 4 + t] = o;
    }
}

// ---------------------------------------------------------------- launch
extern "C" void kernel_launch(void* const* d_in, const int* in_sizes, int n_in,
                              void* d_out, int out_size, void* d_ws, size_t ws_size,
                              hipStream_t stream) {
    const void* Q        = d_in[0];
    const void* K        = d_in[1];
    const int* pad_mask  = (const int*)d_in[2];

    const size_t NEL = (size_t)NB * NSQ * ND;   // 4,194,304
    int* flag = (int*)d_ws;
    u16* base = (u16*)d_ws + 128;
    u16* Qn  = base;
    u16* Kn  = Qn + NEL;
    u16* Q1  = Kn + NEL;
    u16* K1  = Q1 + NEL;
    u16* V1  = K1 + NEL;
    u16* R   = V1 + NEL;
    u16* Wc  = R + NEL;
    u16* Vc  = Wc + (size_t)4 * 1024 * 1024;
    float* maskf = (float*)(Vc + 10 * 1024);
    u16* V1t = Qn;                               // aliases Qn (dead after gemm4)

    detect_kernel<<<dim3(1), dim3(256), 0, stream>>>((const u16*)Q, flag);

    cvt_params_kernel<<<dim3(4106), dim3(256), 0, stream>>>(
        flag, d_in[3], d_in[4], d_in[5], d_in[6],
        d_in[7], d_in[8], d_in[9], d_in[10],
        d_in[11], d_in[12], d_in[13], d_in[14], d_in[15], d_in[16],
        Wc, Vc);

    maskf_kernel<<<dim3(16), dim3(256), 0, stream>>>(pad_mask, maskf);

    ln_in_kernel<<<dim3(2 * NB * NSQ), dim3(256), 0, stream>>>(
        flag, Q, K, Vc, Qn, Kn);

    gemm4_kernel<<<dim3(32, 8, 4), dim3(256), 0, stream>>>(
        Qn, Kn, Wc, Vc, Q1, K1, V1, R);

    vtrans_kernel<<<dim3(32, 16, 2), dim3(256), 0, stream>>>(V1, V1t);

    attn_kernel<<<dim3(NSQ / 64, NH, NB), dim3(256), 0, stream>>>(
        Q1, K1, V1t, maskf, R);

    ln_out_kernel<<<dim3(NB * NSQ), dim3(256), 0, stream>>>(
        flag, Q, R, Vc, d_out);
}

// Round 8
// 262.490 us; speedup vs baseline: 1.5979x; 1.0212x over previous
//
#include <hip/hip_runtime.h>
#include <stdint.h>

#define NB 2
#define NSQ 2048
#define NSK 2048
#define ND 1024
#define NH 16
#define NDH 64

typedef unsigned short u16;
typedef unsigned int u32;
typedef __bf16 bf16x8_t __attribute__((ext_vector_type(8)));
typedef float f32x4_t __attribute__((ext_vector_type(4)));
typedef u32 u32x4_t __attribute__((ext_vector_type(4)));

#define AS1 __attribute__((address_space(1)))
#define AS3 __attribute__((address_space(3)))

__device__ __forceinline__ float bf2f(u16 u) {
    union { float f; u32 i; } v; v.i = ((u32)u) << 16; return v.f;
}
__device__ __forceinline__ u16 f2bf(float x) {
    union { float f; u32 i; } v; v.f = x;
    u32 r = v.i + 0x7fffu + ((v.i >> 16) & 1u);
    return (u16)(r >> 16);
}
__device__ __forceinline__ u32 fbits(float x) {
    union { float f; u32 i; } v; v.f = x; return v.i;
}

// ---------------------------------------------------------------- dtype detect
__global__ __launch_bounds__(256) void detect_kernel(
    const u16* __restrict__ Q, int* __restrict__ flag)
{
    __shared__ int s;
    if (threadIdx.x == 0) s = 0;
    __syncthreads();
    uint2 x = ((const uint2*)Q)[threadIdx.x];
    u16 a0 = x.x & 0xffff, a1 = x.x >> 16, a2 = x.y & 0xffff, a3 = x.y >> 16;
    bool big = (((a0 >> 7) & 0xff) >= 0x8D) || (((a1 >> 7) & 0xff) >= 0x8D) ||
               (((a2 >> 7) & 0xff) >= 0x8D) || (((a3 >> 7) & 0xff) >= 0x8D);
    if (big) s = 1;
    __syncthreads();
    if (threadIdx.x == 0) *flag = s;   // 1 = f32 inputs, 0 = bf16 inputs
}

// ---------------------------------------------------------------- param canon + mask bias
// blocks [0,4096): weights; 4096..4105: vectors; 4106..4109: mask -> bias float
// canonical vec order: bq,bk,bv,bo, ln_q_g,ln_q_b, ln_kv_g,ln_kv_b, ln_f_g,ln_f_b
__global__ __launch_bounds__(256) void cvt_params_kernel(
    const int* __restrict__ flag,
    const void* __restrict__ Wq, const void* __restrict__ Wk,
    const void* __restrict__ Wv, const void* __restrict__ Wo,
    const void* __restrict__ vbq, const void* __restrict__ vbk,
    const void* __restrict__ vbv, const void* __restrict__ vbo,
    const void* __restrict__ g0, const void* __restrict__ b0,
    const void* __restrict__ g1, const void* __restrict__ b1,
    const void* __restrict__ g2, const void* __restrict__ b2,
    const int* __restrict__ pad_mask,
    u16* __restrict__ Wc, u16* __restrict__ Vc, float* __restrict__ maskb)
{
    int blk = blockIdx.x;
    int t = threadIdx.x;
    if (blk >= 4106) {
        int i = (blk - 4106) * 1024 + t * 4;
        int4 mi = *(const int4*)(pad_mask + i);
        float4 mf;
        mf.x = mi.x ? 0.f : -1e9f;
        mf.y = mi.y ? 0.f : -1e9f;
        mf.z = mi.z ? 0.f : -1e9f;
        mf.w = mi.w ? 0.f : -1e9f;
        *(float4*)(maskb + i) = mf;
        return;
    }
    const void* src;
    u16* dst;
    size_t srcoff;
    if (blk < 4096) {
        int w = blk >> 10;
        src = (w == 0) ? Wq : (w == 1) ? Wk : (w == 2) ? Wv : Wo;
        srcoff = (size_t)(blk & 1023) * 1024;
        dst = Wc + (size_t)w * 1024 * 1024 + srcoff;
    } else {
        int v = blk - 4096;
        src = (v == 0) ? vbq : (v == 1) ? vbk : (v == 2) ? vbv : (v == 3) ? vbo :
              (v == 4) ? g0  : (v == 5) ? b0  : (v == 6) ? g1  : (v == 7) ? b1 :
              (v == 8) ? g2  : b2;
        srcoff = 0;
        dst = Vc + (size_t)v * 1024;
    }
    u32 lo, hi;
    if (*flag) {
        float4 x = ((const float4*)src)[srcoff / 4 + t];
        lo = (u32)f2bf(x.x) | ((u32)f2bf(x.y) << 16);
        hi = (u32)f2bf(x.z) | ((u32)f2bf(x.w) << 16);
    } else {
        uint2 x = ((const uint2*)src)[srcoff / 4 + t];
        lo = x.x; hi = x.y;
    }
    uint2 o; o.x = lo; o.y = hi;
    ((uint2*)dst)[t] = o;
}

// ---------------------------------------------------------------- LN (inputs)
__global__ __launch_bounds__(256) void ln_in_kernel(
    const int* __restrict__ flag,
    const void* __restrict__ Q, const void* __restrict__ K,
    const u16* __restrict__ Vc,
    u16* __restrict__ Qn, u16* __restrict__ Kn)
{
    int row = blockIdx.x;
    const void* x; const u16 *g, *bb; u16* y;
    size_t roff;
    if (row < NB * NSQ) {
        x = Q; roff = (size_t)row * ND;
        g = Vc + 4 * 1024; bb = Vc + 5 * 1024;
        y = Qn + roff;
    } else {
        int r2 = row - NB * NSQ;
        x = K; roff = (size_t)r2 * ND;
        g = Vc + 6 * 1024; bb = Vc + 7 * 1024;
        y = Kn + roff;
    }
    int t = threadIdx.x;
    float v0, v1, v2, v3;
    if (*flag) {
        float4 xv = ((const float4*)x)[roff / 4 + t];
        v0 = xv.x; v1 = xv.y; v2 = xv.z; v3 = xv.w;
    } else {
        uint2 ux = ((const uint2*)x)[roff / 4 + t];
        v0 = bf2f(ux.x & 0xffff); v1 = bf2f(ux.x >> 16);
        v2 = bf2f(ux.y & 0xffff); v3 = bf2f(ux.y >> 16);
    }
    float s1 = v0 + v1 + v2 + v3;
    float s2 = v0*v0 + v1*v1 + v2*v2 + v3*v3;
#pragma unroll
    for (int off = 32; off >= 1; off >>= 1) {
        s1 += __shfl_xor(s1, off);
        s2 += __shfl_xor(s2, off);
    }
    __shared__ float r1[4], r2[4];
    int wave = t >> 6;
    if ((t & 63) == 0) { r1[wave] = s1; r2[wave] = s2; }
    __syncthreads();
    float t1 = r1[0] + r1[1] + r1[2] + r1[3];
    float t2 = r2[0] + r2[1] + r2[2] + r2[3];
    float mean = t1 * (1.0f / ND);
    float var  = t2 * (1.0f / ND) - mean * mean;
    float rstd = rsqrtf(var + 1e-5f);
    uint2 ug = ((const uint2*)g)[t];
    uint2 ub = ((const uint2*)bb)[t];
    float y0 = (v0 - mean) * rstd * bf2f(ug.x & 0xffff) + bf2f(ub.x & 0xffff);
    float y1 = (v1 - mean) * rstd * bf2f(ug.x >> 16)    + bf2f(ub.x >> 16);
    float y2 = (v2 - mean) * rstd * bf2f(ug.y & 0xffff) + bf2f(ub.y & 0xffff);
    float y3 = (v3 - mean) * rstd * bf2f(ug.y >> 16)    + bf2f(ub.y >> 16);
    uint2 o;
    o.x = (u32)f2bf(y0) | ((u32)f2bf(y1) << 16);
    o.y = (u32)f2bf(y2) | ((u32)f2bf(y3) << 16);
    ((uint2*)y)[t] = o;
}

// ---------------------------------------------------------------- fused 4x GEMM
// z=0: (Qn@Wq^T+bq)*log2e/32 -> Q1 (exp2 + 1/sqrt(D) folded)
// z=1: Kn@Wk^T+bk -> K1 ; z=2: Kn@Wv^T+bv -> V1 ; z=3: relu(Qn@Wo^T+bo) -> R
__global__ __launch_bounds__(256) void gemm4_kernel(
    const u16* __restrict__ Qn, const u16* __restrict__ Kn,
    const u16* __restrict__ Wc, const u16* __restrict__ Vc,
    u16* __restrict__ Q1, u16* __restrict__ K1, u16* __restrict__ V1,
    u16* __restrict__ R)
{
    int z = blockIdx.z;
    const u16* X    = (z == 0 || z == 3) ? Qn : Kn;
    const u16* W    = Wc + (size_t)z * 1024 * 1024;
    const u16* bias = Vc + (size_t)z * 1024;

    __shared__ u16 sA[128 * 32];
    __shared__ u16 sB[128 * 32];

    int tid  = threadIdx.x;
    int wave = tid >> 6, lane = tid & 63;
    int wm = wave >> 1, wn = wave & 1;
    int m0 = blockIdx.x * 128;
    int n0 = blockIdx.y * 128;

    f32x4_t acc[4][4];
#pragma unroll
    for (int i = 0; i < 4; ++i)
#pragma unroll
        for (int j = 0; j < 4; ++j)
            acc[i][j] = (f32x4_t){0.f, 0.f, 0.f, 0.f};

    int lrow = lane >> 2;
    int lcol = (lane & 3) * 8;

    for (int kb = 0; kb < ND / 32; ++kb) {
        __syncthreads();
        int k0 = kb * 32;
#pragma unroll
        for (int r = 0; r < 2; ++r) {
            int rowb = (r * 4 + wave) * 16;
            const u16* ga = X + (size_t)(m0 + rowb + lrow) * ND + k0 + lcol;
            const u16* gb = W + (size_t)(n0 + rowb + lrow) * ND + k0 + lcol;
            __builtin_amdgcn_global_load_lds(
                (const AS1 u32*)ga, (AS3 u32*)(sA + rowb * 32), 16, 0, 0);
            __builtin_amdgcn_global_load_lds(
                (const AS1 u32*)gb, (AS3 u32*)(sB + rowb * 32), 16, 0, 0);
        }
        __syncthreads();

        bf16x8_t af[4], bfr[4];
#pragma unroll
        for (int tm = 0; tm < 4; ++tm) {
            int rr = wm * 64 + tm * 16 + (lane & 15);
            af[tm] = *(const bf16x8_t*)(sA + rr * 32 + (lane >> 4) * 8);
        }
#pragma unroll
        for (int tn = 0; tn < 4; ++tn) {
            int rr = wn * 64 + tn * 16 + (lane & 15);
            bfr[tn] = *(const bf16x8_t*)(sB + rr * 32 + (lane >> 4) * 8);
        }
#pragma unroll
        for (int tm = 0; tm < 4; ++tm)
#pragma unroll
            for (int tn = 0; tn < 4; ++tn)
                acc[tm][tn] = __builtin_amdgcn_mfma_f32_16x16x32_bf16(
                    af[tm], bfr[tn], acc[tm][tn], 0, 0, 0);
    }

    u16* outp = (z == 0) ? Q1 : (z == 1) ? K1 : (z == 2) ? V1 : R;
#pragma unroll
    for (int tm = 0; tm < 4; ++tm) {
#pragma unroll
        for (int tn = 0; tn < 4; ++tn) {
            int n = n0 + wn * 64 + tn * 16 + (lane & 15);
            float bv_ = bf2f(bias[n]);
#pragma unroll
            for (int r = 0; r < 4; ++r) {
                int m = m0 + wm * 64 + tm * 16 + (lane >> 4) * 4 + r;
                float val = acc[tm][tn][r] + bv_;
                if (z == 0) val *= 0.045105964f;   // (1/32) * log2(e)
                if (z == 3) val = fmaxf(val, 0.f);
                outp[(size_t)m * ND + n] = f2bf(val);
            }
        }
    }
}

// ---------------------------------------------------------------- V transpose
// V1 [b][key][h][d] -> V1t [b][h][d][key]
__global__ __launch_bounds__(256) void vtrans_kernel(
    const u16* __restrict__ V1, u16* __restrict__ V1t)
{
    int kb = blockIdx.x;
    int h  = blockIdx.y;
    int b  = blockIdx.z;
    __shared__ u16 sT[64 * 72];
    int tid = threadIdx.x;
    {
        int row = tid >> 3, seg = tid & 7;
        const u16* gv = V1 + (size_t)(b * NSK + kb * 64 + row) * ND + h * NDH + seg * 8;
        *(uint4*)(sT + row * 72 + seg * 8)        = *(const uint4*)gv;
        *(uint4*)(sT + (row + 32) * 72 + seg * 8) = *(const uint4*)(gv + (size_t)32 * ND);
    }
    __syncthreads();
    int d = tid >> 2, sg = tid & 3;
    u16 buf[16];
#pragma unroll
    for (int i = 0; i < 8; ++i) buf[i]     = sT[(sg * 8 + i) * 72 + d];
#pragma unroll
    for (int i = 0; i < 8; ++i) buf[8 + i] = sT[((sg + 4) * 8 + i) * 72 + d];
    u16* go = V1t + ((size_t)(b * NH + h) * NDH + d) * NSK + kb * 64;
    *(uint4*)(go + sg * 8)       = *(uint4*)buf;
    *(uint4*)(go + (sg + 4) * 8) = *(uint4*)(buf + 8);
}

// ---------------------------------------------------------------- flash attention
// S^T = K.Q^T; DMA double-buffered swizzled LDS; mask folded into MFMA C-init
// (maskb = 0 / -1e9, prefetched); v_perm bf16 packing; hoisted LDS offsets +
// strength-reduced DMA pointers. No-max softmax: p = exp2(s+mb).
__global__ __launch_bounds__(256, 4) void attn_kernel(
    const u16* __restrict__ Q1, const u16* __restrict__ K1,
    const u16* __restrict__ V1t, const float* __restrict__ maskb,
    u16* __restrict__ R)
{
    int q0 = blockIdx.x * 64;
    int h  = blockIdx.y;
    int b  = blockIdx.z;

    __shared__ u16 sK[2][64 * 64];   // [key][seg^(key&7)] swizzled, 8 KB each
    __shared__ u16 sV[2][64 * 64];   // [d][keyseg^(d&7)] swizzled

    int tid  = threadIdx.x;
    int wave = tid >> 6, lane = tid & 63;
    int quad = lane >> 4, l4 = lane & 15;
    int lk = lane >> 3, ls = lane & 7;       // DMA: local row, phys seg
    int gseg = ls ^ lk;                      // global seg feeding phys seg ls

    // Q B-operand fragments (once per block)
    bf16x8_t qf[2];
    {
        const u16* qp = Q1 + (size_t)(b * NSQ + q0 + wave * 16 + l4) * ND + h * NDH;
        qf[0] = *(const bf16x8_t*)(qp + quad * 8);
        qf[1] = *(const bf16x8_t*)(qp + 32 + quad * 8);
    }

    const u16* kbase = K1 + (size_t)b * NSK * ND + h * NDH;
    const u16* vbase = V1t + (size_t)(b * NH + h) * NDH * NSK;
    const float* mbase = maskb + b * NSK;

    // strength-reduced DMA pointers (advance per tile)
    const u16* gk0 = kbase + (size_t)(wave * 16 + lk) * ND + gseg * 8;
    const u16* gk1 = gk0 + (size_t)8 * ND;
    const u16* gv0 = vbase + (size_t)(wave * 16 + lk) * NSK + gseg * 8;
    const u16* gv1 = gv0 + (size_t)8 * NSK;

    // lane-constant LDS fragment offsets (elements); tm adds 1024 (imm 2048B)
    int fragOff[2];
#pragma unroll
    for (int kk = 0; kk < 2; ++kk)
        fragOff[kk] = l4 * 64 + (((kk * 4 + quad) ^ (l4 & 7)) * 8);

    float l_run = 0.f;               // per-lane: q = l4
    f32x4_t acc_o[4];                // O^T C-layout: d = T*16+quad*4+r, q = l4
#pragma unroll
    for (int T = 0; T < 4; ++T) acc_o[T] = (f32x4_t){0.f, 0.f, 0.f, 0.f};

    int srcA = (quad & 1) * 32 + l4;
    int srcB = srcA + 16;
    bool hi = lane >= 32;

    // stage tile 0 into buffer 0
    __builtin_amdgcn_global_load_lds((const AS1 u32*)gk0,
        (AS3 u32*)(&sK[0][(wave * 16) * 64]), 16, 0, 0);
    __builtin_amdgcn_global_load_lds((const AS1 u32*)gk1,
        (AS3 u32*)(&sK[0][(wave * 16 + 8) * 64]), 16, 0, 0);
    __builtin_amdgcn_global_load_lds((const AS1 u32*)gv0,
        (AS3 u32*)(&sV[0][(wave * 16) * 64]), 16, 0, 0);
    __builtin_amdgcn_global_load_lds((const AS1 u32*)gv1,
        (AS3 u32*)(&sV[0][(wave * 16 + 8) * 64]), 16, 0, 0);
    gk0 += (size_t)64 * ND; gk1 += (size_t)64 * ND;
    gv0 += 64; gv1 += 64;

    // prefetch mask-bias fragments for tile 0
    f32x4_t mb[4];
#pragma unroll
    for (int tm = 0; tm < 4; ++tm)
        mb[tm] = *(const f32x4_t*)(mbase + tm * 16 + quad * 4);

    for (int kb = 0; kb < NSK / 64; ++kb) {
        __syncthreads();   // drains DMA(kb) [vmcnt(0) auto]; readers of kb-1 done

        if (kb + 1 < NSK / 64) {
            int bi = (kb + 1) & 1;
            __builtin_amdgcn_global_load_lds((const AS1 u32*)gk0,
                (AS3 u32*)(&sK[bi][(wave * 16) * 64]), 16, 0, 0);
            __builtin_amdgcn_global_load_lds((const AS1 u32*)gk1,
                (AS3 u32*)(&sK[bi][(wave * 16 + 8) * 64]), 16, 0, 0);
            __builtin_amdgcn_global_load_lds((const AS1 u32*)gv0,
                (AS3 u32*)(&sV[bi][(wave * 16) * 64]), 16, 0, 0);
            __builtin_amdgcn_global_load_lds((const AS1 u32*)gv1,
                (AS3 u32*)(&sV[bi][(wave * 16 + 8) * 64]), 16, 0, 0);
            gk0 += (size_t)64 * ND; gk1 += (size_t)64 * ND;
            gv0 += 64; gv1 += 64;
        }

        const u16* kt = sK[kb & 1];
        const u16* vt = sV[kb & 1];

        // S^T = K @ Q^T, C initialized with mask bias (masked -> -1e9 -> p=0)
        f32x4_t accs[4];
#pragma unroll
        for (int tm = 0; tm < 4; ++tm) accs[tm] = mb[tm];
#pragma unroll
        for (int kk = 0; kk < 2; ++kk)
#pragma unroll
            for (int tm = 0; tm < 4; ++tm) {
                bf16x8_t kf = *(const bf16x8_t*)(kt + tm * 1024 + fragOff[kk]);
                accs[tm] = __builtin_amdgcn_mfma_f32_16x16x32_bf16(
                    kf, qf[kk], accs[tm], 0, 0, 0);
            }

        // prefetch mask bias for next tile (consumed next iteration)
        if (kb + 1 < NSK / 64) {
#pragma unroll
            for (int tm = 0; tm < 4; ++tm)
                mb[tm] = *(const f32x4_t*)(mbase + (kb + 1) * 64 + tm * 16 + quad * 4);
        }

        // softmax: p = exp2(s); pack pairs via v_perm (truncate to bf16)
        float lsum = 0.f;
        u32 pk[4][2];
#pragma unroll
        for (int tm = 0; tm < 4; ++tm) {
            float p0 = exp2f(accs[tm][0]);
            float p1 = exp2f(accs[tm][1]);
            float p2 = exp2f(accs[tm][2]);
            float p3 = exp2f(accs[tm][3]);
            lsum += p0 + p1 + p2 + p3;
            pk[tm][0] = __builtin_amdgcn_perm(fbits(p1), fbits(p0), 0x07060302);
            pk[tm][1] = __builtin_amdgcn_perm(fbits(p3), fbits(p2), 0x07060302);
        }
        lsum += __shfl_xor(lsum, 16);
        lsum += __shfl_xor(lsum, 32);
        l_run += lsum;

        // O^T += V^T @ P^T (P^T B-fragment built via cross-lane shuffles)
#pragma unroll
        for (int kk = 0; kk < 2; ++kk) {
            u32 a0 = __shfl((int)pk[kk * 2][0], srcA), a1 = __shfl((int)pk[kk * 2][1], srcA);
            u32 b0 = __shfl((int)pk[kk * 2 + 1][0], srcA), b1 = __shfl((int)pk[kk * 2 + 1][1], srcA);
            u32 c0 = __shfl((int)pk[kk * 2][0], srcB), c1 = __shfl((int)pk[kk * 2][1], srcB);
            u32 d0 = __shfl((int)pk[kk * 2 + 1][0], srcB), d1 = __shfl((int)pk[kk * 2 + 1][1], srcB);
            u32x4_t pr;
            pr.x = hi ? b0 : a0;
            pr.y = hi ? b1 : a1;
            pr.z = hi ? d0 : c0;
            pr.w = hi ? d1 : c1;
            bf16x8_t pf = __builtin_bit_cast(bf16x8_t, pr);
#pragma unroll
            for (int T = 0; T < 4; ++T) {
                bf16x8_t vf = *(const bf16x8_t*)(vt + T * 1024 + fragOff[kk]);
                acc_o[T] = __builtin_amdgcn_mfma_f32_16x16x32_bf16(
                    vf, pf, acc_o[T], 0, 0, 0);
            }
        }
    }

    // epilogue: O[q][d] = acc_o / l ; R += O1 (uint2 RMW)
    float inv = l_run > 0.f ? 1.f / l_run : 0.f;
    u16* rp = R + (size_t)(b * NSQ + q0 + wave * 16 + l4) * ND + h * NDH;
#pragma unroll
    for (int T = 0; T < 4; ++T) {
        u16* p = rp + T * 16 + quad * 4;
        uint2 o2 = *(const uint2*)p;
        float e0 = acc_o[T][0] * inv + bf2f(o2.x & 0xffff);
        float e1 = acc_o[T][1] * inv + bf2f(o2.x >> 16);
        float e2 = acc_o[T][2] * inv + bf2f(o2.y & 0xffff);
        float e3 = acc_o[T][3] * inv + bf2f(o2.y >> 16);
        uint2 on;
        on.x = (u32)f2bf(e0) | ((u32)f2bf(e1) << 16);
        on.y = (u32)f2bf(e2) | ((u32)f2bf(e3) << 16);
        *(uint2*)p = on;
    }
}

// ---------------------------------------------------------------- final LN
__global__ __launch_bounds__(256) void ln_out_kernel(
    const int* __restrict__ flag,
    const void* __restrict__ Q, const u16* __restrict__ R,
    const u16* __restrict__ Vc, void* __restrict__ out)
{
    int row = blockIdx.x;
    size_t roff = (size_t)row * ND;
    int t = threadIdx.x;
    int f = *flag;
    float v0, v1, v2, v3;
    uint2 ur = ((const uint2*)(R + roff))[t];
    if (f) {
        float4 xq = ((const float4*)Q)[roff / 4 + t];
        v0 = xq.x; v1 = xq.y; v2 = xq.z; v3 = xq.w;
    } else {
        uint2 uq = ((const uint2*)Q)[roff / 4 + t];
        v0 = bf2f(uq.x & 0xffff); v1 = bf2f(uq.x >> 16);
        v2 = bf2f(uq.y & 0xffff); v3 = bf2f(uq.y >> 16);
    }
    v0 += bf2f(ur.x & 0xffff); v1 += bf2f(ur.x >> 16);
    v2 += bf2f(ur.y & 0xffff); v3 += bf2f(ur.y >> 16);
    float s1 = v0 + v1 + v2 + v3;
    float s2 = v0*v0 + v1*v1 + v2*v2 + v3*v3;
#pragma unroll
    for (int off = 32; off >= 1; off >>= 1) {
        s1 += __shfl_xor(s1, off);
        s2 += __shfl_xor(s2, off);
    }
    __shared__ float r1[4], r2[4];
    int wave = t >> 6;
    if ((t & 63) == 0) { r1[wave] = s1; r2[wave] = s2; }
    __syncthreads();
    float t1 = r1[0] + r1[1] + r1[2] + r1[3];
    float t2 = r2[0] + r2[1] + r2[2] + r2[3];
    float mean = t1 * (1.0f / ND);
    float var  = t2 * (1.0f / ND) - mean * mean;
    float rstd = rsqrtf(var + 1e-5f);
    const u16* g  = Vc + 8 * 1024;
    const u16* bb = Vc + 9 * 1024;
    uint2 ug = ((const uint2*)g)[t];
    uint2 ub = ((const uint2*)bb)[t];
    float y0 = (v0 - mean) * rstd * bf2f(ug.x & 0xffff) + bf2f(ub.x & 0xffff);
    float y1 = (v1 - mean) * rstd * bf2f(ug.x >> 16)    + bf2f(ub.x >> 16);
    float y2 = (v2 - mean) * rstd * bf2f(ug.y & 0xffff) + bf2f(ub.y & 0xffff);
    float y3 = (v3 - mean) * rstd * bf2f(ug.y >> 16)    + bf2f(ub.y >> 16);
    if (f) {
        float4 o; o.x = y0; o.y = y1; o.z = y2; o.w = y3;
        ((float4*)out)[roff / 4 + t] = o;
    } else {
        uint2 o;
        o.x = (u32)f2bf(y0) | ((u32)f2bf(y1) << 16);
        o.y = (u32)f2bf(y2) | ((u32)f2bf(y3) << 16);
        ((uint2*)out)[roff / 4 + t] = o;
    }
}

// ---------------------------------------------------------------- launch
extern "C" void kernel_launch(void* const* d_in, const int* in_sizes, int n_in,
                              void* d_out, int out_size, void* d_ws, size_t ws_size,
                              hipStream_t stream) {
    const void* Q        = d_in[0];
    const void* K        = d_in[1];
    const int* pad_mask  = (const int*)d_in[2];

    const size_t NEL = (size_t)NB * NSQ * ND;   // 4,194,304
    int* flag = (int*)d_ws;
    u16* base = (u16*)d_ws + 128;
    u16* Qn  = base;
    u16* Kn  = Qn + NEL;
    u16* Q1  = Kn + NEL;
    u16* K1  = Q1 + NEL;
    u16* V1  = K1 + NEL;
    u16* R   = V1 + NEL;
    u16* Wc  = R + NEL;
    u16* Vc  = Wc + (size_t)4 * 1024 * 1024;
    float* maskb = (float*)(Vc + 10 * 1024);
    u16* V1t = Qn;                               // aliases Qn (dead after gemm4)

    detect_kernel<<<dim3(1), dim3(256), 0, stream>>>((const u16*)Q, flag);

    cvt_params_kernel<<<dim3(4110), dim3(256), 0, stream>>>(
        flag, d_in[3], d_in[4], d_in[5], d_in[6],
        d_in[7], d_in[8], d_in[9], d_in[10],
        d_in[11], d_in[12], d_in[13], d_in[14], d_in[15], d_in[16],
        pad_mask, Wc, Vc, maskb);

    ln_in_kernel<<<dim3(2 * NB * NSQ), dim3(256), 0, stream>>>(
        flag, Q, K, Vc, Qn, Kn);

    gemm4_kernel<<<dim3(32, 8, 4), dim3(256), 0, stream>>>(
        Qn, Kn, Wc, Vc, Q1, K1, V1, R);

    vtrans_kernel<<<dim3(32, 16, 2), dim3(256), 0, stream>>>(V1, V1t);

    attn_kernel<<<dim3(NSQ / 64, NH, NB), dim3(256), 0, stream>>>(
        Q1, K1, V1t, maskb, R);

    ln_out_kernel<<<dim3(NB * NSQ), dim3(256), 0, stream>>>(
        flag, Q, R, Vc, d_out);
}

// Round 9
// 257.277 us; speedup vs baseline: 1.6303x; 1.0203x over previous
//
#include <hip/hip_runtime.h>
#include <stdint.h>

#define NB 2
#define NSQ 2048
#define NSK 2048
#define ND 1024
#define NH 16
#define NDH 64

typedef unsigned short u16;
typedef unsigned int u32;
typedef __bf16 bf16x8_t __attribute__((ext_vector_type(8)));
typedef float f32x4_t __attribute__((ext_vector_type(4)));
typedef u32 u32x4_t __attribute__((ext_vector_type(4)));

#define AS1 __attribute__((address_space(1)))
#define AS3 __attribute__((address_space(3)))

__device__ __forceinline__ float bf2f(u16 u) {
    union { float f; u32 i; } v; v.i = ((u32)u) << 16; return v.f;
}
__device__ __forceinline__ u16 f2bf(float x) {
    union { float f; u32 i; } v; v.f = x;
    u32 r = v.i + 0x7fffu + ((v.i >> 16) & 1u);
    return (u16)(r >> 16);
}
__device__ __forceinline__ u32 fbits(float x) {
    union { float f; u32 i; } v; v.f = x; return v.i;
}

// ---------------------------------------------------------------- dtype detect
__global__ __launch_bounds__(256) void detect_kernel(
    const u16* __restrict__ Q, int* __restrict__ flag)
{
    __shared__ int s;
    if (threadIdx.x == 0) s = 0;
    __syncthreads();
    uint2 x = ((const uint2*)Q)[threadIdx.x];
    u16 a0 = x.x & 0xffff, a1 = x.x >> 16, a2 = x.y & 0xffff, a3 = x.y >> 16;
    bool big = (((a0 >> 7) & 0xff) >= 0x8D) || (((a1 >> 7) & 0xff) >= 0x8D) ||
               (((a2 >> 7) & 0xff) >= 0x8D) || (((a3 >> 7) & 0xff) >= 0x8D);
    if (big) s = 1;
    __syncthreads();
    if (threadIdx.x == 0) *flag = s;   // 1 = f32 inputs, 0 = bf16 inputs
}

// ---------------------------------------------------------------- param canon + mask bias
// blocks [0,4096): weights; 4096..4105: vectors; 4106..4109: mask -> bias float
// canonical vec order: bq,bk,bv,bo, ln_q_g,ln_q_b, ln_kv_g,ln_kv_b, ln_f_g,ln_f_b
__global__ __launch_bounds__(256) void cvt_params_kernel(
    const int* __restrict__ flag,
    const void* __restrict__ Wq, const void* __restrict__ Wk,
    const void* __restrict__ Wv, const void* __restrict__ Wo,
    const void* __restrict__ vbq, const void* __restrict__ vbk,
    const void* __restrict__ vbv, const void* __restrict__ vbo,
    const void* __restrict__ g0, const void* __restrict__ b0,
    const void* __restrict__ g1, const void* __restrict__ b1,
    const void* __restrict__ g2, const void* __restrict__ b2,
    const int* __restrict__ pad_mask,
    u16* __restrict__ Wc, u16* __restrict__ Vc, float* __restrict__ maskb)
{
    int blk = blockIdx.x;
    int t = threadIdx.x;
    if (blk >= 4106) {
        int i = (blk - 4106) * 1024 + t * 4;
        int4 mi = *(const int4*)(pad_mask + i);
        float4 mf;
        mf.x = mi.x ? 0.f : -1e9f;
        mf.y = mi.y ? 0.f : -1e9f;
        mf.z = mi.z ? 0.f : -1e9f;
        mf.w = mi.w ? 0.f : -1e9f;
        *(float4*)(maskb + i) = mf;
        return;
    }
    const void* src;
    u16* dst;
    size_t srcoff;
    if (blk < 4096) {
        int w = blk >> 10;
        src = (w == 0) ? Wq : (w == 1) ? Wk : (w == 2) ? Wv : Wo;
        srcoff = (size_t)(blk & 1023) * 1024;
        dst = Wc + (size_t)w * 1024 * 1024 + srcoff;
    } else {
        int v = blk - 4096;
        src = (v == 0) ? vbq : (v == 1) ? vbk : (v == 2) ? vbv : (v == 3) ? vbo :
              (v == 4) ? g0  : (v == 5) ? b0  : (v == 6) ? g1  : (v == 7) ? b1 :
              (v == 8) ? g2  : b2;
        srcoff = 0;
        dst = Vc + (size_t)v * 1024;
    }
    u32 lo, hi;
    if (*flag) {
        float4 x = ((const float4*)src)[srcoff / 4 + t];
        lo = (u32)f2bf(x.x) | ((u32)f2bf(x.y) << 16);
        hi = (u32)f2bf(x.z) | ((u32)f2bf(x.w) << 16);
    } else {
        uint2 x = ((const uint2*)src)[srcoff / 4 + t];
        lo = x.x; hi = x.y;
    }
    uint2 o; o.x = lo; o.y = hi;
    ((uint2*)dst)[t] = o;
}

// ---------------------------------------------------------------- LN (inputs)
__global__ __launch_bounds__(256) void ln_in_kernel(
    const int* __restrict__ flag,
    const void* __restrict__ Q, const void* __restrict__ K,
    const u16* __restrict__ Vc,
    u16* __restrict__ Qn, u16* __restrict__ Kn)
{
    int row = blockIdx.x;
    const void* x; const u16 *g, *bb; u16* y;
    size_t roff;
    if (row < NB * NSQ) {
        x = Q; roff = (size_t)row * ND;
        g = Vc + 4 * 1024; bb = Vc + 5 * 1024;
        y = Qn + roff;
    } else {
        int r2 = row - NB * NSQ;
        x = K; roff = (size_t)r2 * ND;
        g = Vc + 6 * 1024; bb = Vc + 7 * 1024;
        y = Kn + roff;
    }
    int t = threadIdx.x;
    float v0, v1, v2, v3;
    if (*flag) {
        float4 xv = ((const float4*)x)[roff / 4 + t];
        v0 = xv.x; v1 = xv.y; v2 = xv.z; v3 = xv.w;
    } else {
        uint2 ux = ((const uint2*)x)[roff / 4 + t];
        v0 = bf2f(ux.x & 0xffff); v1 = bf2f(ux.x >> 16);
        v2 = bf2f(ux.y & 0xffff); v3 = bf2f(ux.y >> 16);
    }
    float s1 = v0 + v1 + v2 + v3;
    float s2 = v0*v0 + v1*v1 + v2*v2 + v3*v3;
#pragma unroll
    for (int off = 32; off >= 1; off >>= 1) {
        s1 += __shfl_xor(s1, off);
        s2 += __shfl_xor(s2, off);
    }
    __shared__ float r1[4], r2[4];
    int wave = t >> 6;
    if ((t & 63) == 0) { r1[wave] = s1; r2[wave] = s2; }
    __syncthreads();
    float t1 = r1[0] + r1[1] + r1[2] + r1[3];
    float t2 = r2[0] + r2[1] + r2[2] + r2[3];
    float mean = t1 * (1.0f / ND);
    float var  = t2 * (1.0f / ND) - mean * mean;
    float rstd = rsqrtf(var + 1e-5f);
    uint2 ug = ((const uint2*)g)[t];
    uint2 ub = ((const uint2*)bb)[t];
    float y0 = (v0 - mean) * rstd * bf2f(ug.x & 0xffff) + bf2f(ub.x & 0xffff);
    float y1 = (v1 - mean) * rstd * bf2f(ug.x >> 16)    + bf2f(ub.x >> 16);
    float y2 = (v2 - mean) * rstd * bf2f(ug.y & 0xffff) + bf2f(ub.y & 0xffff);
    float y3 = (v3 - mean) * rstd * bf2f(ug.y >> 16)    + bf2f(ub.y >> 16);
    uint2 o;
    o.x = (u32)f2bf(y0) | ((u32)f2bf(y1) << 16);
    o.y = (u32)f2bf(y2) | ((u32)f2bf(y3) << 16);
    ((uint2*)y)[t] = o;
}

// ---------------------------------------------------------------- fused 4x GEMM
// Double-buffered global_load_lds staging (1 barrier/iter, DMA overlaps MFMA).
// z=0: (Qn@Wq^T+bq)*log2e/32 -> Q1 ; z=1: Kn@Wk^T+bk -> K1
// z=2: Kn@Wv^T+bv -> V1t [b][h][d][key] via in-kernel LDS transpose
// z=3: relu(Qn@Wo^T+bo) -> R
__global__ __launch_bounds__(256) void gemm4_kernel(
    const u16* __restrict__ Qn, const u16* __restrict__ Kn,
    const u16* __restrict__ Wc, const u16* __restrict__ Vc,
    u16* __restrict__ Q1, u16* __restrict__ K1, u16* __restrict__ V1t,
    u16* __restrict__ R)
{
    int z = blockIdx.z;
    const u16* X    = (z == 0 || z == 3) ? Qn : Kn;
    const u16* W    = Wc + (size_t)z * 1024 * 1024;
    const u16* bias = Vc + (size_t)z * 1024;

    __shared__ u16 smem[16384];   // 32 KB: A dbuf | B dbuf ; reused as T-tile
    u16* sA0 = smem;
    u16* sA1 = smem + 4096;
    u16* sB0 = smem + 8192;
    u16* sB1 = smem + 12288;

    int tid  = threadIdx.x;
    int wave = tid >> 6, lane = tid & 63;
    int wm = wave >> 1, wn = wave & 1;
    int quad = lane >> 4, l4 = lane & 15;
    int m0 = blockIdx.x * 128;
    int n0 = blockIdx.y * 128;

    f32x4_t acc[4][4];
#pragma unroll
    for (int i = 0; i < 4; ++i)
#pragma unroll
        for (int j = 0; j < 4; ++j)
            acc[i][j] = (f32x4_t){0.f, 0.f, 0.f, 0.f};

    int lrow = lane >> 2;
    int lcol = (lane & 3) * 8;
    int rowb0 = wave * 16;          // rows staged by this wave (r=0)
    int rowb1 = (4 + wave) * 16;    // r=1
    const u16* gA0 = X + (size_t)(m0 + rowb0 + lrow) * ND + lcol;
    const u16* gA1 = X + (size_t)(m0 + rowb1 + lrow) * ND + lcol;
    const u16* gB0 = W + (size_t)(n0 + rowb0 + lrow) * ND + lcol;
    const u16* gB1 = W + (size_t)(n0 + rowb1 + lrow) * ND + lcol;

    // stage tile 0 into buffer 0
    __builtin_amdgcn_global_load_lds((const AS1 u32*)gA0, (AS3 u32*)(sA0 + rowb0 * 32), 16, 0, 0);
    __builtin_amdgcn_global_load_lds((const AS1 u32*)gA1, (AS3 u32*)(sA0 + rowb1 * 32), 16, 0, 0);
    __builtin_amdgcn_global_load_lds((const AS1 u32*)gB0, (AS3 u32*)(sB0 + rowb0 * 32), 16, 0, 0);
    __builtin_amdgcn_global_load_lds((const AS1 u32*)gB1, (AS3 u32*)(sB0 + rowb1 * 32), 16, 0, 0);

    for (int kb = 0; kb < ND / 32; ++kb) {
        __syncthreads();   // drains DMA(kb); prior-iter readers of other buf done

        if (kb + 1 < ND / 32) {
            int k1 = (kb + 1) * 32;
            u16* dA = (kb + 1) & 1 ? sA1 : sA0;
            u16* dB = (kb + 1) & 1 ? sB1 : sB0;
            __builtin_amdgcn_global_load_lds((const AS1 u32*)(gA0 + k1), (AS3 u32*)(dA + rowb0 * 32), 16, 0, 0);
            __builtin_amdgcn_global_load_lds((const AS1 u32*)(gA1 + k1), (AS3 u32*)(dA + rowb1 * 32), 16, 0, 0);
            __builtin_amdgcn_global_load_lds((const AS1 u32*)(gB0 + k1), (AS3 u32*)(dB + rowb0 * 32), 16, 0, 0);
            __builtin_amdgcn_global_load_lds((const AS1 u32*)(gB1 + k1), (AS3 u32*)(dB + rowb1 * 32), 16, 0, 0);
        }

        const u16* a = kb & 1 ? sA1 : sA0;
        const u16* bb_ = kb & 1 ? sB1 : sB0;
        bf16x8_t af[4], bfr[4];
#pragma unroll
        for (int tm = 0; tm < 4; ++tm) {
            int rr = wm * 64 + tm * 16 + l4;
            af[tm] = *(const bf16x8_t*)(a + rr * 32 + quad * 8);
        }
#pragma unroll
        for (int tn = 0; tn < 4; ++tn) {
            int rr = wn * 64 + tn * 16 + l4;
            bfr[tn] = *(const bf16x8_t*)(bb_ + rr * 32 + quad * 8);
        }
#pragma unroll
        for (int tm = 0; tm < 4; ++tm)
#pragma unroll
            for (int tn = 0; tn < 4; ++tn)
                acc[tm][tn] = __builtin_amdgcn_mfma_f32_16x16x32_bf16(
                    af[tm], bfr[tn], acc[tm][tn], 0, 0, 0);
    }

    if (z == 2) {
        // V-transpose epilogue: C[m=key][n=h*64+d] -> V1t[b][h][d][key]
        // two passes over n-halves through a 64 x (128+8) LDS tile
        int bb2 = m0 >> 11, key0 = m0 & 2047;
        __syncthreads();   // all LDS compute reads done before overwrite
        u16* T = smem;     // 64*136 u16 = 17408 B <= 32 KB
#pragma unroll
        for (int h2 = 0; h2 < 2; ++h2) {
            if (wn == h2) {
#pragma unroll
                for (int tn = 0; tn < 4; ++tn) {
                    int nn = tn * 16 + l4;                       // 0..63
                    float bv_ = bf2f(bias[n0 + h2 * 64 + nn]);
#pragma unroll
                    for (int tm = 0; tm < 4; ++tm) {
                        int mb = wm * 64 + tm * 16 + quad * 4;   // 0..124
                        uint2 w;
                        w.x = (u32)f2bf(acc[tm][tn][0] + bv_) |
                              ((u32)f2bf(acc[tm][tn][1] + bv_) << 16);
                        w.y = (u32)f2bf(acc[tm][tn][2] + bv_) |
                              ((u32)f2bf(acc[tm][tn][3] + bv_) << 16);
                        *(uint2*)(T + nn * 136 + mb) = w;
                    }
                }
            }
            __syncthreads();
            {
                int nn = tid >> 2, ch = tid & 3;
                uint4 q0 = *(const uint4*)(T + nn * 136 + ch * 32);
                uint4 q1 = *(const uint4*)(T + nn * 136 + ch * 32 + 8);
                int ng = n0 + h2 * 64 + nn;
                int hh = ng >> 6, dd = ng & 63;
                u16* go = V1t + ((size_t)(bb2 * NH + hh) * NDH + dd) * NSK + key0 + ch * 32;
                *(uint4*)go = q0;
                *(uint4*)(go + 8) = q1;
            }
            __syncthreads();
        }
        return;
    }

    u16* outp = (z == 0) ? Q1 : (z == 1) ? K1 : R;
#pragma unroll
    for (int tm = 0; tm < 4; ++tm) {
#pragma unroll
        for (int tn = 0; tn < 4; ++tn) {
            int n = n0 + wn * 64 + tn * 16 + l4;
            float bv_ = bf2f(bias[n]);
#pragma unroll
            for (int r = 0; r < 4; ++r) {
                int m = m0 + wm * 64 + tm * 16 + quad * 4 + r;
                float val = acc[tm][tn][r] + bv_;
                if (z == 0) val *= 0.045105964f;   // (1/32) * log2(e)
                if (z == 3) val = fmaxf(val, 0.f);
                outp[(size_t)m * ND + n] = f2bf(val);
            }
        }
    }
}

// ---------------------------------------------------------------- flash attention
// S^T = K.Q^T; DMA double-buffered swizzled LDS; mask folded into MFMA C-init
// (maskb = 0 / -1e9, prefetched); v_perm bf16 packing. p = exp2(s+mb).
__global__ __launch_bounds__(256, 4) void attn_kernel(
    const u16* __restrict__ Q1, const u16* __restrict__ K1,
    const u16* __restrict__ V1t, const float* __restrict__ maskb,
    u16* __restrict__ R)
{
    int q0 = blockIdx.x * 64;
    int h  = blockIdx.y;
    int b  = blockIdx.z;

    __shared__ u16 sK[2][64 * 64];   // [key][seg^(key&7)] swizzled, 8 KB each
    __shared__ u16 sV[2][64 * 64];   // [d][keyseg^(d&7)] swizzled

    int tid  = threadIdx.x;
    int wave = tid >> 6, lane = tid & 63;
    int quad = lane >> 4, l4 = lane & 15;
    int lk = lane >> 3, ls = lane & 7;       // DMA: local row, phys seg
    int gseg = ls ^ lk;                      // global seg feeding phys seg ls

    // Q B-operand fragments (once per block)
    bf16x8_t qf[2];
    {
        const u16* qp = Q1 + (size_t)(b * NSQ + q0 + wave * 16 + l4) * ND + h * NDH;
        qf[0] = *(const bf16x8_t*)(qp + quad * 8);
        qf[1] = *(const bf16x8_t*)(qp + 32 + quad * 8);
    }

    const u16* kbase = K1 + (size_t)b * NSK * ND + h * NDH;
    const u16* vbase = V1t + (size_t)(b * NH + h) * NDH * NSK;
    const float* mbase = maskb + b * NSK;

    // strength-reduced DMA pointers (advance per tile)
    const u16* gk0 = kbase + (size_t)(wave * 16 + lk) * ND + gseg * 8;
    const u16* gk1 = gk0 + (size_t)8 * ND;
    const u16* gv0 = vbase + (size_t)(wave * 16 + lk) * NSK + gseg * 8;
    const u16* gv1 = gv0 + (size_t)8 * NSK;

    // lane-constant LDS fragment offsets (elements); tm adds 1024 (imm 2048B)
    int fragOff[2];
#pragma unroll
    for (int kk = 0; kk < 2; ++kk)
        fragOff[kk] = l4 * 64 + (((kk * 4 + quad) ^ (l4 & 7)) * 8);

    float l_run = 0.f;               // per-lane: q = l4
    f32x4_t acc_o[4];                // O^T C-layout: d = T*16+quad*4+r, q = l4
#pragma unroll
    for (int T = 0; T < 4; ++T) acc_o[T] = (f32x4_t){0.f, 0.f, 0.f, 0.f};

    int srcA = (quad & 1) * 32 + l4;
    int srcB = srcA + 16;
    bool hi = lane >= 32;

    // stage tile 0 into buffer 0
    __builtin_amdgcn_global_load_lds((const AS1 u32*)gk0,
        (AS3 u32*)(&sK[0][(wave * 16) * 64]), 16, 0, 0);
    __builtin_amdgcn_global_load_lds((const AS1 u32*)gk1,
        (AS3 u32*)(&sK[0][(wave * 16 + 8) * 64]), 16, 0, 0);
    __builtin_amdgcn_global_load_lds((const AS1 u32*)gv0,
        (AS3 u32*)(&sV[0][(wave * 16) * 64]), 16, 0, 0);
    __builtin_amdgcn_global_load_lds((const AS1 u32*)gv1,
        (AS3 u32*)(&sV[0][(wave * 16 + 8) * 64]), 16, 0, 0);
    gk0 += (size_t)64 * ND; gk1 += (size_t)64 * ND;
    gv0 += 64; gv1 += 64;

    // prefetch mask-bias fragments for tile 0
    f32x4_t mb[4];
#pragma unroll
    for (int tm = 0; tm < 4; ++tm)
        mb[tm] = *(const f32x4_t*)(mbase + tm * 16 + quad * 4);

    for (int kb = 0; kb < NSK / 64; ++kb) {
        __syncthreads();   // drains DMA(kb) [vmcnt(0) auto]; readers of kb-1 done

        if (kb + 1 < NSK / 64) {
            int bi = (kb + 1) & 1;
            __builtin_amdgcn_global_load_lds((const AS1 u32*)gk0,
                (AS3 u32*)(&sK[bi][(wave * 16) * 64]), 16, 0, 0);
            __builtin_amdgcn_global_load_lds((const AS1 u32*)gk1,
                (AS3 u32*)(&sK[bi][(wave * 16 + 8) * 64]), 16, 0, 0);
            __builtin_amdgcn_global_load_lds((const AS1 u32*)gv0,
                (AS3 u32*)(&sV[bi][(wave * 16) * 64]), 16, 0, 0);
            __builtin_amdgcn_global_load_lds((const AS1 u32*)gv1,
                (AS3 u32*)(&sV[bi][(wave * 16 + 8) * 64]), 16, 0, 0);
            gk0 += (size_t)64 * ND; gk1 += (size_t)64 * ND;
            gv0 += 64; gv1 += 64;
        }

        const u16* kt = sK[kb & 1];
        const u16* vt = sV[kb & 1];

        // S^T = K @ Q^T, C initialized with mask bias (masked -> -1e9 -> p=0)
        f32x4_t accs[4];
#pragma unroll
        for (int tm = 0; tm < 4; ++tm) accs[tm] = mb[tm];
#pragma unroll
        for (int kk = 0; kk < 2; ++kk)
#pragma unroll
            for (int tm = 0; tm < 4; ++tm) {
                bf16x8_t kf = *(const bf16x8_t*)(kt + tm * 1024 + fragOff[kk]);
                accs[tm] = __builtin_amdgcn_mfma_f32_16x16x32_bf16(
                    kf, qf[kk], accs[tm], 0, 0, 0);
            }

        // prefetch mask bias for next tile (consumed next iteration)
        if (kb + 1 < NSK / 64) {
#pragma unroll
            for (int tm = 0; tm < 4; ++tm)
                mb[tm] = *(const f32x4_t*)(mbase + (kb + 1) * 64 + tm * 16 + quad * 4);
        }

        // softmax: p = exp2(s); pack pairs via v_perm (truncate to bf16)
        float lsum = 0.f;
        u32 pk[4][2];
#pragma unroll
        for (int tm = 0; tm < 4; ++tm) {
            float p0 = exp2f(accs[tm][0]);
            float p1 = exp2f(accs[tm][1]);
            float p2 = exp2f(accs[tm][2]);
            float p3 = exp2f(accs[tm][3]);
            lsum += p0 + p1 + p2 + p3;
            pk[tm][0] = __builtin_amdgcn_perm(fbits(p1), fbits(p0), 0x07060302);
            pk[tm][1] = __builtin_amdgcn_perm(fbits(p3), fbits(p2), 0x07060302);
        }
        lsum += __shfl_xor(lsum, 16);
        lsum += __shfl_xor(lsum, 32);
        l_run += lsum;

        // O^T += V^T @ P^T (P^T B-fragment built via cross-lane shuffles)
#pragma unroll
        for (int kk = 0; kk < 2; ++kk) {
            u32 a0 = __shfl((int)pk[kk * 2][0], srcA), a1 = __shfl((int)pk[kk * 2][1], srcA);
            u32 b0 = __shfl((int)pk[kk * 2 + 1][0], srcA), b1 = __shfl((int)pk[kk * 2 + 1][1], srcA);
            u32 c0 = __shfl((int)pk[kk * 2][0], srcB), c1 = __shfl((int)pk[kk * 2][1], srcB);
            u32 d0 = __shfl((int)pk[kk * 2 + 1][0], srcB), d1 = __shfl((int)pk[kk * 2 + 1][1], srcB);
            u32x4_t pr;
            pr.x = hi ? b0 : a0;
            pr.y = hi ? b1 : a1;
            pr.z = hi ? d0 : c0;
            pr.w = hi ? d1 : c1;
            bf16x8_t pf = __builtin_bit_cast(bf16x8_t, pr);
#pragma unroll
            for (int T = 0; T < 4; ++T) {
                bf16x8_t vf = *(const bf16x8_t*)(vt + T * 1024 + fragOff[kk]);
                acc_o[T] = __builtin_amdgcn_mfma_f32_16x16x32_bf16(
                    vf, pf, acc_o[T], 0, 0, 0);
            }
        }
    }

    // epilogue: O[q][d] = acc_o / l ; R += O1 (uint2 RMW)
    float inv = l_run > 0.f ? 1.f / l_run : 0.f;
    u16* rp = R + (size_t)(b * NSQ + q0 + wave * 16 + l4) * ND + h * NDH;
#pragma unroll
    for (int T = 0; T < 4; ++T) {
        u16* p = rp + T * 16 + quad * 4;
        uint2 o2 = *(const uint2*)p;
        float e0 = acc_o[T][0] * inv + bf2f(o2.x & 0xffff);
        float e1 = acc_o[T][1] * inv + bf2f(o2.x >> 16);
        float e2 = acc_o[T][2] * inv + bf2f(o2.y & 0xffff);
        float e3 = acc_o[T][3] * inv + bf2f(o2.y >> 16);
        uint2 on;
        on.x = (u32)f2bf(e0) | ((u32)f2bf(e1) << 16);
        on.y = (u32)f2bf(e2) | ((u32)f2bf(e3) << 16);
        *(uint2*)p = on;
    }
}

// ---------------------------------------------------------------- final LN
__global__ __launch_bounds__(256) void ln_out_kernel(
    const int* __restrict__ flag,
    const void* __restrict__ Q, const u16* __restrict__ R,
    const u16* __restrict__ Vc, void* __restrict__ out)
{
    int row = blockIdx.x;
    size_t roff = (size_t)row * ND;
    int t = threadIdx.x;
    int f = *flag;
    float v0, v1, v2, v3;
    uint2 ur = ((const uint2*)(R + roff))[t];
    if (f) {
        float4 xq = ((const float4*)Q)[roff / 4 + t];
        v0 = xq.x; v1 = xq.y; v2 = xq.z; v3 = xq.w;
    } else {
        uint2 uq = ((const uint2*)Q)[roff / 4 + t];
        v0 = bf2f(uq.x & 0xffff); v1 = bf2f(uq.x >> 16);
        v2 = bf2f(uq.y & 0xffff); v3 = bf2f(uq.y >> 16);
    }
    v0 += bf2f(ur.x & 0xffff); v1 += bf2f(ur.x >> 16);
    v2 += bf2f(ur.y & 0xffff); v3 += bf2f(ur.y >> 16);
    float s1 = v0 + v1 + v2 + v3;
    float s2 = v0*v0 + v1*v1 + v2*v2 + v3*v3;
#pragma unroll
    for (int off = 32; off >= 1; off >>= 1) {
        s1 += __shfl_xor(s1, off);
        s2 += __shfl_xor(s2, off);
    }
    __shared__ float r1[4], r2[4];
    int wave = t >> 6;
    if ((t & 63) == 0) { r1[wave] = s1; r2[wave] = s2; }
    __syncthreads();
    float t1 = r1[0] + r1[1] + r1[2] + r1[3];
    float t2 = r2[0] + r2[1] + r2[2] + r2[3];
    float mean = t1 * (1.0f / ND);
    float var  = t2 * (1.0f / ND) - mean * mean;
    float rstd = rsqrtf(var + 1e-5f);
    const u16* g  = Vc + 8 * 1024;
    const u16* bb = Vc + 9 * 1024;
    uint2 ug = ((const uint2*)g)[t];
    uint2 ub = ((const uint2*)bb)[t];
    float y0 = (v0 - mean) * rstd * bf2f(ug.x & 0xffff) + bf2f(ub.x & 0xffff);
    float y1 = (v1 - mean) * rstd * bf2f(ug.x >> 16)    + bf2f(ub.x >> 16);
    float y2 = (v2 - mean) * rstd * bf2f(ug.y & 0xffff) + bf2f(ub.y & 0xffff);
    float y3 = (v3 - mean) * rstd * bf2f(ug.y >> 16)    + bf2f(ub.y >> 16);
    if (f) {
        float4 o; o.x = y0; o.y = y1; o.z = y2; o.w = y3;
        ((float4*)out)[roff / 4 + t] = o;
    } else {
        uint2 o;
        o.x = (u32)f2bf(y0) | ((u32)f2bf(y1) << 16);
        o.y = (u32)f2bf(y2) | ((u32)f2bf(y3) << 16);
        ((uint2*)out)[roff / 4 + t] = o;
    }
}

// ---------------------------------------------------------------- launch
extern "C" void kernel_launch(void* const* d_in, const int* in_sizes, int n_in,
                              void* d_out, int out_size, void* d_ws, size_t ws_size,
                              hipStream_t stream) {
    const void* Q        = d_in[0];
    const void* K        = d_in[1];
    const int* pad_mask  = (const int*)d_in[2];

    const size_t NEL = (size_t)NB * NSQ * ND;   // 4,194,304
    int* flag = (int*)d_ws;
    u16* base = (u16*)d_ws + 128;
    u16* Qn  = base;
    u16* Kn  = Qn + NEL;
    u16* Q1  = Kn + NEL;
    u16* K1  = Q1 + NEL;
    u16* V1t = K1 + NEL;                         // [b][h][d][key] direct from gemm
    u16* R   = V1t + NEL;
    u16* Wc  = R + NEL;
    u16* Vc  = Wc + (size_t)4 * 1024 * 1024;
    float* maskb = (float*)(Vc + 10 * 1024);

    detect_kernel<<<dim3(1), dim3(256), 0, stream>>>((const u16*)Q, flag);

    cvt_params_kernel<<<dim3(4110), dim3(256), 0, stream>>>(
        flag, d_in[3], d_in[4], d_in[5], d_in[6],
        d_in[7], d_in[8], d_in[9], d_in[10],
        d_in[11], d_in[12], d_in[13], d_in[14], d_in[15], d_in[16],
        pad_mask, Wc, Vc, maskb);

    ln_in_kernel<<<dim3(2 * NB * NSQ), dim3(256), 0, stream>>>(
        flag, Q, K, Vc, Qn, Kn);

    gemm4_kernel<<<dim3(32, 8, 4), dim3(256), 0, stream>>>(
        Qn, Kn, Wc, Vc, Q1, K1, V1t, R);

    attn_kernel<<<dim3(NSQ / 64, NH, NB), dim3(256), 0, stream>>>(
        Q1, K1, V1t, maskb, R);

    ln_out_kernel<<<dim3(NB * NSQ), dim3(256), 0, stream>>>(
        flag, Q, R, Vc, d_out);
}

// Round 10
// 254.081 us; speedup vs baseline: 1.6508x; 1.0126x over previous
//
#include <hip/hip_runtime.h>
#include <stdint.h>

#define NB 2
#define NSQ 2048
#define NSK 2048
#define ND 1024
#define NH 16
#define NDH 64

typedef unsigned short u16;
typedef unsigned int u32;
typedef __bf16 bf16x8_t __attribute__((ext_vector_type(8)));
typedef float f32x4_t __attribute__((ext_vector_type(4)));
typedef u32 u32x4_t __attribute__((ext_vector_type(4)));

#define AS1 __attribute__((address_space(1)))
#define AS3 __attribute__((address_space(3)))

__device__ __forceinline__ float bf2f(u16 u) {
    union { float f; u32 i; } v; v.i = ((u32)u) << 16; return v.f;
}
__device__ __forceinline__ u16 f2bf(float x) {
    union { float f; u32 i; } v; v.f = x;
    u32 r = v.i + 0x7fffu + ((v.i >> 16) & 1u);
    return (u16)(r >> 16);
}
__device__ __forceinline__ u32 fbits(float x) {
    union { float f; u32 i; } v; v.f = x; return v.i;
}

// ---------------------------------------------------------------- dtype detect
__global__ __launch_bounds__(256) void detect_kernel(
    const u16* __restrict__ Q, int* __restrict__ flag)
{
    __shared__ int s;
    if (threadIdx.x == 0) s = 0;
    __syncthreads();
    uint2 x = ((const uint2*)Q)[threadIdx.x];
    u16 a0 = x.x & 0xffff, a1 = x.x >> 16, a2 = x.y & 0xffff, a3 = x.y >> 16;
    bool big = (((a0 >> 7) & 0xff) >= 0x8D) || (((a1 >> 7) & 0xff) >= 0x8D) ||
               (((a2 >> 7) & 0xff) >= 0x8D) || (((a3 >> 7) & 0xff) >= 0x8D);
    if (big) s = 1;
    __syncthreads();
    if (threadIdx.x == 0) *flag = s;   // 1 = f32 inputs, 0 = bf16 inputs
}

// ---------------------------------------------------------------- param canon
// blocks [0,4096): weights; 4096..4105: vectors
// canonical vec order: bq,bk,bv,bo, ln_q_g,ln_q_b, ln_kv_g,ln_kv_b, ln_f_g,ln_f_b
__global__ __launch_bounds__(256) void cvt_params_kernel(
    const int* __restrict__ flag,
    const void* __restrict__ Wq, const void* __restrict__ Wk,
    const void* __restrict__ Wv, const void* __restrict__ Wo,
    const void* __restrict__ vbq, const void* __restrict__ vbk,
    const void* __restrict__ vbv, const void* __restrict__ vbo,
    const void* __restrict__ g0, const void* __restrict__ b0,
    const void* __restrict__ g1, const void* __restrict__ b1,
    const void* __restrict__ g2, const void* __restrict__ b2,
    u16* __restrict__ Wc, u16* __restrict__ Vc)
{
    int blk = blockIdx.x;
    int t = threadIdx.x;
    const void* src;
    u16* dst;
    size_t srcoff;
    if (blk < 4096) {
        int w = blk >> 10;
        src = (w == 0) ? Wq : (w == 1) ? Wk : (w == 2) ? Wv : Wo;
        srcoff = (size_t)(blk & 1023) * 1024;
        dst = Wc + (size_t)w * 1024 * 1024 + srcoff;
    } else {
        int v = blk - 4096;
        src = (v == 0) ? vbq : (v == 1) ? vbk : (v == 2) ? vbv : (v == 3) ? vbo :
              (v == 4) ? g0  : (v == 5) ? b0  : (v == 6) ? g1  : (v == 7) ? b1 :
              (v == 8) ? g2  : b2;
        srcoff = 0;
        dst = Vc + (size_t)v * 1024;
    }
    u32 lo, hi;
    if (*flag) {
        float4 x = ((const float4*)src)[srcoff / 4 + t];
        lo = (u32)f2bf(x.x) | ((u32)f2bf(x.y) << 16);
        hi = (u32)f2bf(x.z) | ((u32)f2bf(x.w) << 16);
    } else {
        uint2 x = ((const uint2*)src)[srcoff / 4 + t];
        lo = x.x; hi = x.y;
    }
    uint2 o; o.x = lo; o.y = hi;
    ((uint2*)dst)[t] = o;
}

// ---------------------------------------------------------------- key index compaction
// per batch: idx[b][j] = j-th unmasked key; cnt[b] = number of unmasked keys
__global__ __launch_bounds__(256) void idx_kernel(
    const int* __restrict__ mask, int* __restrict__ idx, int* __restrict__ cnt)
{
    int b = blockIdx.x;
    const int* m = mask + b * NSK;
    int t = threadIdx.x;
    int loc[8]; int s = 0;
#pragma unroll
    for (int i = 0; i < 8; ++i) { loc[i] = (m[t * 8 + i] != 0); s += loc[i]; }
    __shared__ int ps[256];
    ps[t] = s;
    __syncthreads();
    for (int off = 1; off < 256; off <<= 1) {
        int v = (t >= off) ? ps[t - off] : 0;
        __syncthreads();
        ps[t] += v;
        __syncthreads();
    }
    int run = ps[t] - s;   // exclusive prefix
#pragma unroll
    for (int i = 0; i < 8; ++i)
        if (loc[i]) idx[b * NSK + run++] = t * 8 + i;
    if (t == 255) cnt[b] = ps[255];
}

// ---------------------------------------------------------------- LN (inputs)
__global__ __launch_bounds__(256) void ln_in_kernel(
    const int* __restrict__ flag,
    const void* __restrict__ Q, const void* __restrict__ K,
    const u16* __restrict__ Vc,
    u16* __restrict__ Qn, u16* __restrict__ Kn)
{
    int row = blockIdx.x;
    const void* x; const u16 *g, *bb; u16* y;
    size_t roff;
    if (row < NB * NSQ) {
        x = Q; roff = (size_t)row * ND;
        g = Vc + 4 * 1024; bb = Vc + 5 * 1024;
        y = Qn + roff;
    } else {
        int r2 = row - NB * NSQ;
        x = K; roff = (size_t)r2 * ND;
        g = Vc + 6 * 1024; bb = Vc + 7 * 1024;
        y = Kn + roff;
    }
    int t = threadIdx.x;
    float v0, v1, v2, v3;
    if (*flag) {
        float4 xv = ((const float4*)x)[roff / 4 + t];
        v0 = xv.x; v1 = xv.y; v2 = xv.z; v3 = xv.w;
    } else {
        uint2 ux = ((const uint2*)x)[roff / 4 + t];
        v0 = bf2f(ux.x & 0xffff); v1 = bf2f(ux.x >> 16);
        v2 = bf2f(ux.y & 0xffff); v3 = bf2f(ux.y >> 16);
    }
    float s1 = v0 + v1 + v2 + v3;
    float s2 = v0*v0 + v1*v1 + v2*v2 + v3*v3;
#pragma unroll
    for (int off = 32; off >= 1; off >>= 1) {
        s1 += __shfl_xor(s1, off);
        s2 += __shfl_xor(s2, off);
    }
    __shared__ float r1[4], r2[4];
    int wave = t >> 6;
    if ((t & 63) == 0) { r1[wave] = s1; r2[wave] = s2; }
    __syncthreads();
    float t1 = r1[0] + r1[1] + r1[2] + r1[3];
    float t2 = r2[0] + r2[1] + r2[2] + r2[3];
    float mean = t1 * (1.0f / ND);
    float var  = t2 * (1.0f / ND) - mean * mean;
    float rstd = rsqrtf(var + 1e-5f);
    uint2 ug = ((const uint2*)g)[t];
    uint2 ub = ((const uint2*)bb)[t];
    float y0 = (v0 - mean) * rstd * bf2f(ug.x & 0xffff) + bf2f(ub.x & 0xffff);
    float y1 = (v1 - mean) * rstd * bf2f(ug.x >> 16)    + bf2f(ub.x >> 16);
    float y2 = (v2 - mean) * rstd * bf2f(ug.y & 0xffff) + bf2f(ub.y & 0xffff);
    float y3 = (v3 - mean) * rstd * bf2f(ug.y >> 16)    + bf2f(ub.y >> 16);
    uint2 o;
    o.x = (u32)f2bf(y0) | ((u32)f2bf(y1) << 16);
    o.y = (u32)f2bf(y2) | ((u32)f2bf(y3) << 16);
    ((uint2*)y)[t] = o;
}

// ---------------------------------------------------------------- fused 4x GEMM
// Double-buffered global_load_lds staging (1 barrier/iter).
// z=0: (Qn@Wq^T+bq)*log2e/32 -> Q1 ; z=1: Kn@Wk^T+bk -> K1
// z=2: Kn@Wv^T+bv -> V1 (row layout) ; z=3: relu(Qn@Wo^T+bo) -> R
__global__ __launch_bounds__(256) void gemm4_kernel(
    const u16* __restrict__ Qn, const u16* __restrict__ Kn,
    const u16* __restrict__ Wc, const u16* __restrict__ Vc,
    u16* __restrict__ Q1, u16* __restrict__ K1, u16* __restrict__ V1,
    u16* __restrict__ R)
{
    int z = blockIdx.z;
    const u16* X    = (z == 0 || z == 3) ? Qn : Kn;
    const u16* W    = Wc + (size_t)z * 1024 * 1024;
    const u16* bias = Vc + (size_t)z * 1024;

    __shared__ u16 smem[16384];   // 32 KB: A dbuf | B dbuf
    u16* sA0 = smem;
    u16* sA1 = smem + 4096;
    u16* sB0 = smem + 8192;
    u16* sB1 = smem + 12288;

    int tid  = threadIdx.x;
    int wave = tid >> 6, lane = tid & 63;
    int wm = wave >> 1, wn = wave & 1;
    int quad = lane >> 4, l4 = lane & 15;
    int m0 = blockIdx.x * 128;
    int n0 = blockIdx.y * 128;

    f32x4_t acc[4][4];
#pragma unroll
    for (int i = 0; i < 4; ++i)
#pragma unroll
        for (int j = 0; j < 4; ++j)
            acc[i][j] = (f32x4_t){0.f, 0.f, 0.f, 0.f};

    int lrow = lane >> 2;
    int lcol = (lane & 3) * 8;
    int rowb0 = wave * 16;
    int rowb1 = (4 + wave) * 16;
    const u16* gA0 = X + (size_t)(m0 + rowb0 + lrow) * ND + lcol;
    const u16* gA1 = X + (size_t)(m0 + rowb1 + lrow) * ND + lcol;
    const u16* gB0 = W + (size_t)(n0 + rowb0 + lrow) * ND + lcol;
    const u16* gB1 = W + (size_t)(n0 + rowb1 + lrow) * ND + lcol;

    __builtin_amdgcn_global_load_lds((const AS1 u32*)gA0, (AS3 u32*)(sA0 + rowb0 * 32), 16, 0, 0);
    __builtin_amdgcn_global_load_lds((const AS1 u32*)gA1, (AS3 u32*)(sA0 + rowb1 * 32), 16, 0, 0);
    __builtin_amdgcn_global_load_lds((const AS1 u32*)gB0, (AS3 u32*)(sB0 + rowb0 * 32), 16, 0, 0);
    __builtin_amdgcn_global_load_lds((const AS1 u32*)gB1, (AS3 u32*)(sB0 + rowb1 * 32), 16, 0, 0);

    for (int kb = 0; kb < ND / 32; ++kb) {
        __syncthreads();

        if (kb + 1 < ND / 32) {
            int k1 = (kb + 1) * 32;
            u16* dA = (kb + 1) & 1 ? sA1 : sA0;
            u16* dB = (kb + 1) & 1 ? sB1 : sB0;
            __builtin_amdgcn_global_load_lds((const AS1 u32*)(gA0 + k1), (AS3 u32*)(dA + rowb0 * 32), 16, 0, 0);
            __builtin_amdgcn_global_load_lds((const AS1 u32*)(gA1 + k1), (AS3 u32*)(dA + rowb1 * 32), 16, 0, 0);
            __builtin_amdgcn_global_load_lds((const AS1 u32*)(gB0 + k1), (AS3 u32*)(dB + rowb0 * 32), 16, 0, 0);
            __builtin_amdgcn_global_load_lds((const AS1 u32*)(gB1 + k1), (AS3 u32*)(dB + rowb1 * 32), 16, 0, 0);
        }

        const u16* a = kb & 1 ? sA1 : sA0;
        const u16* bb_ = kb & 1 ? sB1 : sB0;
        bf16x8_t af[4], bfr[4];
#pragma unroll
        for (int tm = 0; tm < 4; ++tm) {
            int rr = wm * 64 + tm * 16 + l4;
            af[tm] = *(const bf16x8_t*)(a + rr * 32 + quad * 8);
        }
#pragma unroll
        for (int tn = 0; tn < 4; ++tn) {
            int rr = wn * 64 + tn * 16 + l4;
            bfr[tn] = *(const bf16x8_t*)(bb_ + rr * 32 + quad * 8);
        }
#pragma unroll
        for (int tm = 0; tm < 4; ++tm)
#pragma unroll
            for (int tn = 0; tn < 4; ++tn)
                acc[tm][tn] = __builtin_amdgcn_mfma_f32_16x16x32_bf16(
                    af[tm], bfr[tn], acc[tm][tn], 0, 0, 0);
    }

    u16* outp = (z == 0) ? Q1 : (z == 1) ? K1 : (z == 2) ? V1 : R;
#pragma unroll
    for (int tm = 0; tm < 4; ++tm) {
#pragma unroll
        for (int tn = 0; tn < 4; ++tn) {
            int n = n0 + wn * 64 + tn * 16 + l4;
            float bv_ = bf2f(bias[n]);
#pragma unroll
            for (int r = 0; r < 4; ++r) {
                int m = m0 + wm * 64 + tm * 16 + quad * 4 + r;
                float val = acc[tm][tn][r] + bv_;
                if (z == 0) val *= 0.045105964f;   // (1/32) * log2(e)
                if (z == 3) val = fmaxf(val, 0.f);
                outp[(size_t)m * ND + n] = f2bf(val);
            }
        }
    }
}

// ---------------------------------------------------------------- K gather (compaction)
// Kc[b][j] = K1[b][idx[j]] for j < cnt; zeros for j in [cnt, roundup64(cnt))
__global__ __launch_bounds__(256) void gather_k_kernel(
    const u16* __restrict__ K1, const int* __restrict__ idx,
    const int* __restrict__ cnt, u16* __restrict__ Kc)
{
    int b = blockIdx.y;
    int c = cnt[b];
    int cPad = (c + 63) & ~63;
    int jb = blockIdx.x * 16;
    if (jb >= cPad) return;
    int t = threadIdx.x;
    int row = t >> 4;          // 0..15
    int seg = t & 15;          // 8 uint4 each
    int j = jb + row;
    if (j >= cPad) return;
    bool z = (j >= c);
    const u16* src = z ? (const u16*)0
        : K1 + ((size_t)b * NSK + idx[(size_t)b * NSK + j]) * ND;
    u16* dst = Kc + ((size_t)b * NSK + j) * ND;
#pragma unroll
    for (int i = 0; i < 8; ++i) {
        int off = (seg * 8 + i) * 8;
        uint4 v = z ? (uint4){0, 0, 0, 0} : *(const uint4*)(src + off);
        *(uint4*)(dst + off) = v;
    }
}

// ---------------------------------------------------------------- V^T gather (compaction)
// Vct[b][h][d][j] = V1[b][idx[j]][h*64+d] ; zeros for j in [cnt, roundup64)
__global__ __launch_bounds__(256) void gather_vt_kernel(
    const u16* __restrict__ V1, const int* __restrict__ idx,
    const int* __restrict__ cnt, u16* __restrict__ Vct)
{
    int kb = blockIdx.x;
    int h  = blockIdx.y;
    int b  = blockIdx.z;
    int c = cnt[b];
    int cPad = (c + 63) & ~63;
    if (kb * 64 >= cPad) return;
    __shared__ u16 sT[64 * 72];
    int tid = threadIdx.x;
    {
        int row = tid >> 3, seg = tid & 7;
        int j1 = kb * 64 + row, j2 = j1 + 32;
        uint4 v1 = {0, 0, 0, 0}, v2 = {0, 0, 0, 0};
        if (j1 < c) v1 = *(const uint4*)(V1 +
            ((size_t)b * NSK + idx[(size_t)b * NSK + j1]) * ND + h * NDH + seg * 8);
        if (j2 < c) v2 = *(const uint4*)(V1 +
            ((size_t)b * NSK + idx[(size_t)b * NSK + j2]) * ND + h * NDH + seg * 8);
        *(uint4*)(sT + row * 72 + seg * 8) = v1;
        *(uint4*)(sT + (row + 32) * 72 + seg * 8) = v2;
    }
    __syncthreads();
    int d = tid >> 2, sg = tid & 3;
    u16 buf[16];
#pragma unroll
    for (int i = 0; i < 8; ++i) buf[i]     = sT[(sg * 8 + i) * 72 + d];
#pragma unroll
    for (int i = 0; i < 8; ++i) buf[8 + i] = sT[((sg + 4) * 8 + i) * 72 + d];
    u16* go = Vct + ((size_t)(b * NH + h) * NDH + d) * NSK + kb * 64;
    *(uint4*)(go + sg * 8)       = *(uint4*)buf;
    *(uint4*)(go + (sg + 4) * 8) = *(uint4*)(buf + 8);
}

// ---------------------------------------------------------------- flash attention
// Compacted keys: loop runs ceil(cnt/64) tiles; no mask in inner loop; tail
// tile masked by inline C-init bias (key >= cnt -> -1e9 -> p = 0).
// S^T = K.Q^T; DMA double-buffered swizzled LDS; v_perm bf16 packing.
__global__ __launch_bounds__(256, 4) void attn_kernel(
    const u16* __restrict__ Q1, const u16* __restrict__ Kc,
    const u16* __restrict__ Vct, const int* __restrict__ cnt,
    u16* __restrict__ R)
{
    int q0 = blockIdx.x * 64;
    int h  = blockIdx.y;
    int b  = blockIdx.z;

    __shared__ u16 sK[2][64 * 64];
    __shared__ u16 sV[2][64 * 64];

    int tid  = threadIdx.x;
    int wave = tid >> 6, lane = tid & 63;
    int quad = lane >> 4, l4 = lane & 15;
    int lk = lane >> 3, ls = lane & 7;
    int gseg = ls ^ lk;

    int c  = cnt[b];
    int nt = (c + 63) >> 6;

    bf16x8_t qf[2];
    {
        const u16* qp = Q1 + (size_t)(b * NSQ + q0 + wave * 16 + l4) * ND + h * NDH;
        qf[0] = *(const bf16x8_t*)(qp + quad * 8);
        qf[1] = *(const bf16x8_t*)(qp + 32 + quad * 8);
    }

    const u16* kbase = Kc + (size_t)b * NSK * ND + h * NDH;
    const u16* vbase = Vct + (size_t)(b * NH + h) * NDH * NSK;

    const u16* gk0 = kbase + (size_t)(wave * 16 + lk) * ND + gseg * 8;
    const u16* gk1 = gk0 + (size_t)8 * ND;
    const u16* gv0 = vbase + (size_t)(wave * 16 + lk) * NSK + gseg * 8;
    const u16* gv1 = gv0 + (size_t)8 * NSK;

    int fragOff[2];
#pragma unroll
    for (int kk = 0; kk < 2; ++kk)
        fragOff[kk] = l4 * 64 + (((kk * 4 + quad) ^ (l4 & 7)) * 8);

    float l_run = 0.f;
    f32x4_t acc_o[4];
#pragma unroll
    for (int T = 0; T < 4; ++T) acc_o[T] = (f32x4_t){0.f, 0.f, 0.f, 0.f};

    int srcA = (quad & 1) * 32 + l4;
    int srcB = srcA + 16;
    bool hi = lane >= 32;

    if (nt > 0) {
        __builtin_amdgcn_global_load_lds((const AS1 u32*)gk0,
            (AS3 u32*)(&sK[0][(wave * 16) * 64]), 16, 0, 0);
        __builtin_amdgcn_global_load_lds((const AS1 u32*)gk1,
            (AS3 u32*)(&sK[0][(wave * 16 + 8) * 64]), 16, 0, 0);
        __builtin_amdgcn_global_load_lds((const AS1 u32*)gv0,
            (AS3 u32*)(&sV[0][(wave * 16) * 64]), 16, 0, 0);
        __builtin_amdgcn_global_load_lds((const AS1 u32*)gv1,
            (AS3 u32*)(&sV[0][(wave * 16 + 8) * 64]), 16, 0, 0);
        gk0 += (size_t)64 * ND; gk1 += (size_t)64 * ND;
        gv0 += 64; gv1 += 64;

        for (int kb = 0; kb < nt; ++kb) {
            __syncthreads();

            if (kb + 1 < nt) {
                int bi = (kb + 1) & 1;
                __builtin_amdgcn_global_load_lds((const AS1 u32*)gk0,
                    (AS3 u32*)(&sK[bi][(wave * 16) * 64]), 16, 0, 0);
                __builtin_amdgcn_global_load_lds((const AS1 u32*)gk1,
                    (AS3 u32*)(&sK[bi][(wave * 16 + 8) * 64]), 16, 0, 0);
                __builtin_amdgcn_global_load_lds((const AS1 u32*)gv0,
                    (AS3 u32*)(&sV[bi][(wave * 16) * 64]), 16, 0, 0);
                __builtin_amdgcn_global_load_lds((const AS1 u32*)gv1,
                    (AS3 u32*)(&sV[bi][(wave * 16 + 8) * 64]), 16, 0, 0);
                gk0 += (size_t)64 * ND; gk1 += (size_t)64 * ND;
                gv0 += 64; gv1 += 64;
            }

            const u16* kt = sK[kb & 1];
            const u16* vt = sV[kb & 1];

            // C-init: 0 for valid keys; -1e9 on tail keys >= cnt
            f32x4_t accs[4];
            if (kb == nt - 1) {
#pragma unroll
                for (int tm = 0; tm < 4; ++tm) {
                    int key = kb * 64 + tm * 16 + quad * 4;
#pragma unroll
                    for (int r = 0; r < 4; ++r)
                        accs[tm][r] = (key + r < c) ? 0.f : -1e9f;
                }
            } else {
#pragma unroll
                for (int tm = 0; tm < 4; ++tm)
                    accs[tm] = (f32x4_t){0.f, 0.f, 0.f, 0.f};
            }
#pragma unroll
            for (int kk = 0; kk < 2; ++kk)
#pragma unroll
                for (int tm = 0; tm < 4; ++tm) {
                    bf16x8_t kf = *(const bf16x8_t*)(kt + tm * 1024 + fragOff[kk]);
                    accs[tm] = __builtin_amdgcn_mfma_f32_16x16x32_bf16(
                        kf, qf[kk], accs[tm], 0, 0, 0);
                }

            // softmax: p = exp2(s) (Q pre-scaled by log2e/32); v_perm packing
            float lsum = 0.f;
            u32 pk[4][2];
#pragma unroll
            for (int tm = 0; tm < 4; ++tm) {
                float p0 = exp2f(accs[tm][0]);
                float p1 = exp2f(accs[tm][1]);
                float p2 = exp2f(accs[tm][2]);
                float p3 = exp2f(accs[tm][3]);
                lsum += p0 + p1 + p2 + p3;
                pk[tm][0] = __builtin_amdgcn_perm(fbits(p1), fbits(p0), 0x07060302);
                pk[tm][1] = __builtin_amdgcn_perm(fbits(p3), fbits(p2), 0x07060302);
            }
            lsum += __shfl_xor(lsum, 16);
            lsum += __shfl_xor(lsum, 32);
            l_run += lsum;

            // O^T += V^T @ P^T
#pragma unroll
            for (int kk = 0; kk < 2; ++kk) {
                u32 a0 = __shfl((int)pk[kk * 2][0], srcA), a1 = __shfl((int)pk[kk * 2][1], srcA);
                u32 b0 = __shfl((int)pk[kk * 2 + 1][0], srcA), b1 = __shfl((int)pk[kk * 2 + 1][1], srcA);
                u32 c0 = __shfl((int)pk[kk * 2][0], srcB), c1 = __shfl((int)pk[kk * 2][1], srcB);
                u32 d0 = __shfl((int)pk[kk * 2 + 1][0], srcB), d1 = __shfl((int)pk[kk * 2 + 1][1], srcB);
                u32x4_t pr;
                pr.x = hi ? b0 : a0;
                pr.y = hi ? b1 : a1;
                pr.z = hi ? d0 : c0;
                pr.w = hi ? d1 : c1;
                bf16x8_t pf = __builtin_bit_cast(bf16x8_t, pr);
#pragma unroll
                for (int T = 0; T < 4; ++T) {
                    bf16x8_t vf = *(const bf16x8_t*)(vt + T * 1024 + fragOff[kk]);
                    acc_o[T] = __builtin_amdgcn_mfma_f32_16x16x32_bf16(
                        vf, pf, acc_o[T], 0, 0, 0);
                }
            }
        }
    }

    // epilogue: O[q][d] = acc_o / l ; R += O1 (uint2 RMW)
    float inv = l_run > 0.f ? 1.f / l_run : 0.f;
    u16* rp = R + (size_t)(b * NSQ + q0 + wave * 16 + l4) * ND + h * NDH;
#pragma unroll
    for (int T = 0; T < 4; ++T) {
        u16* p = rp + T * 16 + quad * 4;
        uint2 o2 = *(const uint2*)p;
        float e0 = acc_o[T][0] * inv + bf2f(o2.x & 0xffff);
        float e1 = acc_o[T][1] * inv + bf2f(o2.x >> 16);
        float e2 = acc_o[T][2] * inv + bf2f(o2.y & 0xffff);
        float e3 = acc_o[T][3] * inv + bf2f(o2.y >> 16);
        uint2 on;
        on.x = (u32)f2bf(e0) | ((u32)f2bf(e1) << 16);
        on.y = (u32)f2bf(e2) | ((u32)f2bf(e3) << 16);
        *(uint2*)p = on;
    }
}

// ---------------------------------------------------------------- final LN
__global__ __launch_bounds__(256) void ln_out_kernel(
    const int* __restrict__ flag,
    const void* __restrict__ Q, const u16* __restrict__ R,
    const u16* __restrict__ Vc, void* __restrict__ out)
{
    int row = blockIdx.x;
    size_t roff = (size_t)row * ND;
    int t = threadIdx.x;
    int f = *flag;
    float v0, v1, v2, v3;
    uint2 ur = ((const uint2*)(R + roff))[t];
    if (f) {
        float4 xq = ((const float4*)Q)[roff / 4 + t];
        v0 = xq.x; v1 = xq.y; v2 = xq.z; v3 = xq.w;
    } else {
        uint2 uq = ((const uint2*)Q)[roff / 4 + t];
        v0 = bf2f(uq.x & 0xffff); v1 = bf2f(uq.x >> 16);
        v2 = bf2f(uq.y & 0xffff); v3 = bf2f(uq.y >> 16);
    }
    v0 += bf2f(ur.x & 0xffff); v1 += bf2f(ur.x >> 16);
    v2 += bf2f(ur.y & 0xffff); v3 += bf2f(ur.y >> 16);
    float s1 = v0 + v1 + v2 + v3;
    float s2 = v0*v0 + v1*v1 + v2*v2 + v3*v3;
#pragma unroll
    for (int off = 32; off >= 1; off >>= 1) {
        s1 += __shfl_xor(s1, off);
        s2 += __shfl_xor(s2, off);
    }
    __shared__ float r1[4], r2[4];
    int wave = t >> 6;
    if ((t & 63) == 0) { r1[wave] = s1; r2[wave] = s2; }
    __syncthreads();
    float t1 = r1[0] + r1[1] + r1[2] + r1[3];
    float t2 = r2[0] + r2[1] + r2[2] + r2[3];
    float mean = t1 * (1.0f / ND);
    float var  = t2 * (1.0f / ND) - mean * mean;
    float rstd = rsqrtf(var + 1e-5f);
    const u16* g  = Vc + 8 * 1024;
    const u16* bb = Vc + 9 * 1024;
    uint2 ug = ((const uint2*)g)[t];
    uint2 ub = ((const uint2*)bb)[t];
    float y0 = (v0 - mean) * rstd * bf2f(ug.x & 0xffff) + bf2f(ub.x & 0xffff);
    float y1 = (v1 - mean) * rstd * bf2f(ug.x >> 16)    + bf2f(ub.x >> 16);
    float y2 = (v2 - mean) * rstd * bf2f(ug.y & 0xffff) + bf2f(ub.y & 0xffff);
    float y3 = (v3 - mean) * rstd * bf2f(ug.y >> 16)    + bf2f(ub.y >> 16);
    if (f) {
        float4 o; o.x = y0; o.y = y1; o.z = y2; o.w = y3;
        ((float4*)out)[roff / 4 + t] = o;
    } else {
        uint2 o;
        o.x = (u32)f2bf(y0) | ((u32)f2bf(y1) << 16);
        o.y = (u32)f2bf(y2) | ((u32)f2bf(y3) << 16);
        ((uint2*)out)[roff / 4 + t] = o;
    }
}

// ---------------------------------------------------------------- launch
extern "C" void kernel_launch(void* const* d_in, const int* in_sizes, int n_in,
                              void* d_out, int out_size, void* d_ws, size_t ws_size,
                              hipStream_t stream) {
    const void* Q        = d_in[0];
    const void* K        = d_in[1];
    const int* pad_mask  = (const int*)d_in[2];

    const size_t NEL = (size_t)NB * NSQ * ND;   // 4,194,304
    int* flag = (int*)d_ws;                      // [0]
    int* cnt  = flag + 1;                        // [1..2]
    int* idx  = flag + 4;                        // 2 x 2048 ints
    u16* base = (u16*)(idx + 4096);              // 16-byte aligned
    u16* Qn  = base;
    u16* Kn  = Qn + NEL;
    u16* Q1  = Kn + NEL;
    u16* K1  = Q1 + NEL;
    u16* V1  = K1 + NEL;
    u16* R   = V1 + NEL;
    u16* Wc  = R + NEL;
    u16* Vc  = Wc + (size_t)4 * 1024 * 1024;
    u16* Kc  = Qn;                               // aliases Qn (dead after gemm4)
    u16* Vct = Kn;                               // aliases Kn (dead after gemm4)

    detect_kernel<<<dim3(1), dim3(256), 0, stream>>>((const u16*)Q, flag);

    cvt_params_kernel<<<dim3(4106), dim3(256), 0, stream>>>(
        flag, d_in[3], d_in[4], d_in[5], d_in[6],
        d_in[7], d_in[8], d_in[9], d_in[10],
        d_in[11], d_in[12], d_in[13], d_in[14], d_in[15], d_in[16],
        Wc, Vc);

    idx_kernel<<<dim3(NB), dim3(256), 0, stream>>>(pad_mask, idx, cnt);

    ln_in_kernel<<<dim3(2 * NB * NSQ), dim3(256), 0, stream>>>(
        flag, Q, K, Vc, Qn, Kn);

    gemm4_kernel<<<dim3(32, 8, 4), dim3(256), 0, stream>>>(
        Qn, Kn, Wc, Vc, Q1, K1, V1, R);

    gather_k_kernel<<<dim3(128, NB), dim3(256), 0, stream>>>(K1, idx, cnt, Kc);

    gather_vt_kernel<<<dim3(32, NH, NB), dim3(256), 0, stream>>>(V1, idx, cnt, Vct);

    attn_kernel<<<dim3(NSQ / 64, NH, NB), dim3(256), 0, stream>>>(
        Q1, Kc, Vct, cnt, R);

    ln_out_kernel<<<dim3(NB * NSQ), dim3(256), 0, stream>>>(
        flag, Q, R, Vc, d_out);
}